// Round 10
// baseline (280.685 us; speedup 1.0000x reference)
//
#include <hip/hip_runtime.h>
#include <hip/hip_bf16.h>

namespace {

constexpr int kB = 1024;      // batch
constexpr int kNU = 1024;     // num users
constexpr int kNB = 2048;     // num businesses
constexpr int kNN = 3072;     // total nodes
constexpr int kE = 16384;     // raw edges
constexpr int kET = kE + kNN; // edges + self loops = 19456
constexpr int kH = 768;
constexpr int kHeads = 8;
constexpr int kS2 = 8;        // GAT2 split-K factor (XCD-pinned K-chunks)

typedef __attribute__((ext_vector_type(8))) short bf16x8_t;
typedef __attribute__((ext_vector_type(4))) float f32x4_t;

__device__ __forceinline__ float tof(float x) { return x; }
__device__ __forceinline__ float tof(__hip_bfloat16 x) { return __bfloat162float(x); }
__device__ __forceinline__ void stor(float* p, float v) { *p = v; }
__device__ __forceinline__ void stor(__hip_bfloat16* p, float v) { *p = __float2bfloat16(v); }

__device__ __forceinline__ float blo(unsigned u) {
  union { unsigned u; float f; } c; c.u = u << 16; return c.f;
}
__device__ __forceinline__ float bhi(unsigned u) {
  union { unsigned u; float f; } c; c.u = u & 0xffff0000u; return c.f;
}

__device__ __forceinline__ unsigned pk2(float a, float b) {
  union { __hip_bfloat16 h[2]; unsigned u; } c;
  c.h[0] = __float2bfloat16(a); c.h[1] = __float2bfloat16(b);
  return c.u;
}

__device__ __forceinline__ void gload_lds16(const void* g, void* l) {
  __builtin_amdgcn_global_load_lds(
      (const __attribute__((address_space(1))) void*)g,
      (__attribute__((address_space(3))) void*)l, 16, 0, 0);
}

// counted-vmcnt wait: keep the newest-stage loads in flight (T4)
template <int G>
__device__ __forceinline__ void wait_stage(bool more) {
  if (more) {
    if constexpr (G == 2) asm volatile("s_waitcnt vmcnt(2)" ::: "memory");
    else if constexpr (G == 3) asm volatile("s_waitcnt vmcnt(3)" ::: "memory");
    else asm volatile("s_waitcnt vmcnt(4)" ::: "memory");
  } else {
    asm volatile("s_waitcnt vmcnt(0)" ::: "memory");
  }
  __builtin_amdgcn_sched_barrier(0);
  asm volatile("s_barrier" ::: "memory");
  __builtin_amdgcn_sched_barrier(0);
}

// ---------------- 3-buffer counted-vmcnt MFMA GEMM body ----------------
// Per K-step: vmcnt(G) [tile kt landed; kt+1 in flight] + s_barrier ->
// stage kt+2 (into buf used at kt-1) -> ds_read(buf kt%3) -> MFMA.
template <int BM, int BN, int FM, int FN, typename TC>
__device__ __forceinline__ void gemm_body(
    const __hip_bfloat16* __restrict__ A, const __hip_bfloat16* __restrict__ Bt,
    const float* __restrict__ bias, TC* __restrict__ C,
    int K, int lda, int ldc, int act, int bx, int by) {
  __shared__ __align__(16) __hip_bfloat16 As[3][BM][32];
  __shared__ __align__(16) __hip_bfloat16 Bs[3][BN][32];
  constexpr int G = BM / 64 + BN / 64;
  const int t = threadIdx.x;
  const int w = t >> 6, lane = t & 63;
  const int wm = w >> 1, wn = w & 1;
  const int bm = by * BM, bn = bx * BN;
  const int lr = lane & 15, lg = lane >> 4;

  f32x4_t acc[FM][FN];
#pragma unroll
  for (int m = 0; m < FM; ++m)
#pragma unroll
    for (int n = 0; n < FN; ++n) acc[m][n] = (f32x4_t){0.f, 0.f, 0.f, 0.f};

  auto stage = [&](int buf, int kt) {
    const int k0 = kt << 5;
#pragma unroll
    for (int i = 0; i < BM / 64; ++i) {
      int L = i * 256 + t;
      gload_lds16(A + (size_t)(bm + (L >> 2)) * lda + k0 + (L & 3) * 8,
                  (char*)(&As[buf][0][0]) + ((size_t)(i * 256 + w * 64)) * 16);
    }
#pragma unroll
    for (int i = 0; i < BN / 64; ++i) {
      int L = i * 256 + t;
      gload_lds16(Bt + (size_t)(bn + (L >> 2)) * K + k0 + (L & 3) * 8,
                  (char*)(&Bs[buf][0][0]) + ((size_t)(i * 256 + w * 64)) * 16);
    }
  };

  const int NT = K >> 5;
  stage(0, 0);
  if (NT > 1) stage(1, 1);
  int cur = 0;
  for (int kt = 0; kt < NT; ++kt) {
    wait_stage<G>(kt + 1 < NT);
    if (kt + 2 < NT) {
      int sb = cur + 2; if (sb >= 3) sb -= 3;
      stage(sb, kt + 2);
    }
    bf16x8_t af[FM], bv[FN];
#pragma unroll
    for (int m = 0; m < FM; ++m)
      af[m] = *(const bf16x8_t*)&As[cur][wm * FM * 16 + m * 16 + lr][lg * 8];
#pragma unroll
    for (int n = 0; n < FN; ++n)
      bv[n] = *(const bf16x8_t*)&Bs[cur][wn * FN * 16 + n * 16 + lr][lg * 8];
#pragma unroll
    for (int m = 0; m < FM; ++m)
#pragma unroll
      for (int n = 0; n < FN; ++n)
        acc[m][n] = __builtin_amdgcn_mfma_f32_16x16x32_bf16(af[m], bv[n], acc[m][n], 0, 0, 0);
    cur = (cur == 2) ? 0 : cur + 1;
  }

#pragma unroll
  for (int m = 0; m < FM; ++m) {
    const int row0 = bm + wm * FM * 16 + m * 16 + lg * 4;
#pragma unroll
    for (int n = 0; n < FN; ++n) {
      const int cn = bn + wn * FN * 16 + n * 16 + lr;
      const float bvv = bias ? bias[cn] : 0.f;
#pragma unroll
      for (int r = 0; r < 4; ++r) {
        float v = acc[m][n][r] + bvv;
        if (act) v = fmaxf(v, 0.f);
        stor(&C[(size_t)(row0 + r) * ldc + cn], v);
      }
    }
  }
}

__device__ __forceinline__ void swz_xy(bool mfast, int& bx, int& by) {
  const int nwg = gridDim.x * gridDim.y;
  const int orig = blockIdx.y * gridDim.x + blockIdx.x;
  const int swz = (orig & 7) * (nwg >> 3) + (orig >> 3);
  if (mfast) { by = swz % gridDim.y; bx = swz / gridDim.y; }
  else       { bx = swz % gridDim.x; by = swz / gridDim.x; }
}

template <int BM, int BN, int FM, int FN>
__global__ __launch_bounds__(256) void mfma_gemm_dual(
    const __hip_bfloat16* __restrict__ A0, const __hip_bfloat16* __restrict__ Bt0,
    const float* __restrict__ bias0, float* __restrict__ C0,
    const __hip_bfloat16* __restrict__ A1, const __hip_bfloat16* __restrict__ Bt1,
    const float* __restrict__ bias1, float* __restrict__ C1,
    int N, int K) {
  int bx, by;
  swz_xy(true, bx, by);
  const __hip_bfloat16* A = blockIdx.z ? A1 : A0;
  const __hip_bfloat16* Bt = blockIdx.z ? Bt1 : Bt0;
  const float* bias = blockIdx.z ? bias1 : bias0;
  float* C = blockIdx.z ? C1 : C0;
  gemm_body<BM, BN, FM, FN, float>(A, Bt, bias, C, K, K, N, 0, bx, by);
}

// per-head projection, HEAD->XCD PINNED: blockIdx.x = head = dispatch%8 = XCD.
template <int BM, int BN, int FM, int FN>
__global__ __launch_bounds__(256) void gemm_head(
    const __hip_bfloat16* __restrict__ y, const __hip_bfloat16* __restrict__ W1t,
    const float* __restrict__ b1, __hip_bfloat16* __restrict__ x2) {
  const int hd = blockIdx.x;            // 0..7
  const int tile = blockIdx.y;          // 0..143
  const int bx = tile % (kH / BN);
  const int by = tile / (kH / BN);
  gemm_body<BM, BN, FM, FN, __hip_bfloat16>(
      y + (size_t)hd * kH, W1t + (size_t)hd * kH * kH, b1 + hd * kH,
      x2 + (size_t)hd * kH, kH, kHeads * kH, kHeads * kH, 1, bx, by);
}

// split-K, K-CHUNK->XCD PINNED (3-buffer counted-vmcnt)
template <int BM, int BN, int FM, int FN, int S>
__global__ __launch_bounds__(256) void mfma_gemm_kpin(
    const __hip_bfloat16* __restrict__ A, const __hip_bfloat16* __restrict__ Bt,
    float* __restrict__ Cpart, int M, int N, int K) {
  __shared__ __align__(16) __hip_bfloat16 As[3][BM][32];
  __shared__ __align__(16) __hip_bfloat16 Bs[3][BN][32];
  constexpr int G = BM / 64 + BN / 64;
  const int kc = blockIdx.x;
  const int tile = blockIdx.y;
  const int tilesN = N / BN;
  const int bx = tile % tilesN;
  const int by = tile / tilesN;
  const int KC = K / S;
  const int kbeg = kc * KC;
  const int t = threadIdx.x;
  const int w = t >> 6, lane = t & 63;
  const int wm = w >> 1, wn = w & 1;
  const int bm = by * BM, bn = bx * BN;
  const int lr = lane & 15, lg = lane >> 4;

  f32x4_t acc[FM][FN];
#pragma unroll
  for (int m = 0; m < FM; ++m)
#pragma unroll
    for (int n = 0; n < FN; ++n) acc[m][n] = (f32x4_t){0.f, 0.f, 0.f, 0.f};

  auto stage = [&](int buf, int kt) {
    const int k0 = kbeg + (kt << 5);
#pragma unroll
    for (int i = 0; i < BM / 64; ++i) {
      int L = i * 256 + t;
      gload_lds16(A + (size_t)(bm + (L >> 2)) * K + k0 + (L & 3) * 8,
                  (char*)(&As[buf][0][0]) + ((size_t)(i * 256 + w * 64)) * 16);
    }
#pragma unroll
    for (int i = 0; i < BN / 64; ++i) {
      int L = i * 256 + t;
      gload_lds16(Bt + (size_t)(bn + (L >> 2)) * K + k0 + (L & 3) * 8,
                  (char*)(&Bs[buf][0][0]) + ((size_t)(i * 256 + w * 64)) * 16);
    }
  };

  const int NT = KC >> 5;
  stage(0, 0);
  if (NT > 1) stage(1, 1);
  int cur = 0;
  for (int kt = 0; kt < NT; ++kt) {
    wait_stage<G>(kt + 1 < NT);
    if (kt + 2 < NT) {
      int sb = cur + 2; if (sb >= 3) sb -= 3;
      stage(sb, kt + 2);
    }
    bf16x8_t af[FM], bv[FN];
#pragma unroll
    for (int m = 0; m < FM; ++m)
      af[m] = *(const bf16x8_t*)&As[cur][wm * FM * 16 + m * 16 + lr][lg * 8];
#pragma unroll
    for (int n = 0; n < FN; ++n)
      bv[n] = *(const bf16x8_t*)&Bs[cur][wn * FN * 16 + n * 16 + lr][lg * 8];
#pragma unroll
    for (int m = 0; m < FM; ++m)
#pragma unroll
      for (int n = 0; n < FN; ++n)
        acc[m][n] = __builtin_amdgcn_mfma_f32_16x16x32_bf16(af[m], bv[n], acc[m][n], 0, 0, 0);
    cur = (cur == 2) ? 0 : cur + 1;
  }

  float* Cp = Cpart + (size_t)kc * M * N;
#pragma unroll
  for (int m = 0; m < FM; ++m) {
    const int row0 = bm + wm * FM * 16 + m * 16 + lg * 4;
#pragma unroll
    for (int n = 0; n < FN; ++n) {
      const int cn = bn + wn * FN * 16 + n * 16 + lr;
#pragma unroll
      for (int r = 0; r < 4; ++r) Cp[(size_t)(row0 + r) * N + cn] = acc[m][n][r];
    }
  }
}

// generic split-K (swizzled, 3-buffer counted-vmcnt) for the MLP GEMMs
template <int BM, int BN, int FM, int FN>
__global__ __launch_bounds__(256) void mfma_gemm_splitk(
    const __hip_bfloat16* __restrict__ A, const __hip_bfloat16* __restrict__ Bt,
    float* __restrict__ Cpart, int M, int N, int K, int KC) {
  __shared__ __align__(16) __hip_bfloat16 As[3][BM][32];
  __shared__ __align__(16) __hip_bfloat16 Bs[3][BN][32];
  constexpr int G = BM / 64 + BN / 64;
  int bx, by;
  swz_xy(false, bx, by);
  const int t = threadIdx.x;
  const int w = t >> 6, lane = t & 63;
  const int wm = w >> 1, wn = w & 1;
  const int bm = by * BM, bn = bx * BN;
  const int kbeg = blockIdx.z * KC;
  const int lr = lane & 15, lg = lane >> 4;

  f32x4_t acc[FM][FN];
#pragma unroll
  for (int m = 0; m < FM; ++m)
#pragma unroll
    for (int n = 0; n < FN; ++n) acc[m][n] = (f32x4_t){0.f, 0.f, 0.f, 0.f};

  auto stage = [&](int buf, int kt) {
    const int k0 = kbeg + (kt << 5);
#pragma unroll
    for (int i = 0; i < BM / 64; ++i) {
      int L = i * 256 + t;
      gload_lds16(A + (size_t)(bm + (L >> 2)) * K + k0 + (L & 3) * 8,
                  (char*)(&As[buf][0][0]) + ((size_t)(i * 256 + w * 64)) * 16);
    }
#pragma unroll
    for (int i = 0; i < BN / 64; ++i) {
      int L = i * 256 + t;
      gload_lds16(Bt + (size_t)(bn + (L >> 2)) * K + k0 + (L & 3) * 8,
                  (char*)(&Bs[buf][0][0]) + ((size_t)(i * 256 + w * 64)) * 16);
    }
  };

  const int NT = KC >> 5;
  stage(0, 0);
  if (NT > 1) stage(1, 1);
  int cur = 0;
  for (int kt = 0; kt < NT; ++kt) {
    wait_stage<G>(kt + 1 < NT);
    if (kt + 2 < NT) {
      int sb = cur + 2; if (sb >= 3) sb -= 3;
      stage(sb, kt + 2);
    }
    bf16x8_t af[FM], bv[FN];
#pragma unroll
    for (int m = 0; m < FM; ++m)
      af[m] = *(const bf16x8_t*)&As[cur][wm * FM * 16 + m * 16 + lr][lg * 8];
#pragma unroll
    for (int n = 0; n < FN; ++n)
      bv[n] = *(const bf16x8_t*)&Bs[cur][wn * FN * 16 + n * 16 + lr][lg * 8];
#pragma unroll
    for (int m = 0; m < FM; ++m)
#pragma unroll
      for (int n = 0; n < FN; ++n)
        acc[m][n] = __builtin_amdgcn_mfma_f32_16x16x32_bf16(af[m], bv[n], acc[m][n], 0, 0, 0);
    cur = (cur == 2) ? 0 : cur + 1;
  }

  float* Cp = Cpart + (size_t)blockIdx.z * M * N;
#pragma unroll
  for (int m = 0; m < FM; ++m) {
    const int row0 = bm + wm * FM * 16 + m * 16 + lg * 4;
#pragma unroll
    for (int n = 0; n < FN; ++n) {
      const int cn = bn + wn * FN * 16 + n * 16 + lr;
#pragma unroll
      for (int r = 0; r < 4; ++r) Cp[(size_t)(row0 + r) * N + cn] = acc[m][n][r];
    }
  }
}

// ---------------- fused split-K reduce (S=8) + scores2 ----------------
__global__ __launch_bounds__(192) void reduce_scores2_kernel(
    const float* __restrict__ part, const float* __restrict__ att_src,
    const float* __restrict__ att_dst, __hip_bfloat16* __restrict__ h2,
    float* __restrict__ s_src, float* __restrict__ s_dst) {
  __shared__ float redS[3], redD[3];
  const int row = blockIdx.x;
  const int t = threadIdx.x;
  const int c = t * 4;
  const float* p = part + (size_t)row * kH + c;
  float4 s = *(const float4*)p;
#pragma unroll
  for (int z = 1; z < kS2; ++z) {
    float4 qv = *(const float4*)(p + (size_t)z * kNN * kH);
    s.x += qv.x; s.y += qv.y; s.z += qv.z; s.w += qv.w;
  }
  __hip_bfloat16 b0 = __float2bfloat16(s.x), b1 = __float2bfloat16(s.y);
  __hip_bfloat16 b2 = __float2bfloat16(s.z), b3 = __float2bfloat16(s.w);
  __hip_bfloat16* o = h2 + (size_t)row * kH + c;
  o[0] = b0; o[1] = b1; o[2] = b2; o[3] = b3;
  float f0 = tof(b0), f1 = tof(b1), f2 = tof(b2), f3 = tof(b3);
  float ss = f0 * att_src[c] + f1 * att_src[c + 1] + f2 * att_src[c + 2] + f3 * att_src[c + 3];
  float sd = f0 * att_dst[c] + f1 * att_dst[c + 1] + f2 * att_dst[c + 2] + f3 * att_dst[c + 3];
#pragma unroll
  for (int off = 32; off; off >>= 1) { ss += __shfl_down(ss, off); sd += __shfl_down(sd, off); }
  if ((t & 63) == 0) { redS[t >> 6] = ss; redD[t >> 6] = sd; }
  __syncthreads();
  if (t == 0) {
    s_src[row] = redS[0] + redS[1] + redS[2];
    s_dst[row] = redD[0] + redD[1] + redD[2];
  }
}

// ---------------- split-K reduce + bias + relu -> bf16 (for Wf1) ----------------
__global__ void reduce_relu_kernel(const float* __restrict__ part,
                                   const float* __restrict__ bias,
                                   __hip_bfloat16* __restrict__ outb, int MN4, int N) {
  int i = blockIdx.x * 256 + threadIdx.x;
  if (i >= MN4) return;
  float4 s = ((const float4*)part)[i];
  float4 p = ((const float4*)part)[(size_t)MN4 + i];
  int c = (i * 4) % N;
  float v0 = fmaxf(s.x + p.x + bias[c], 0.f);
  float v1 = fmaxf(s.y + p.y + bias[c + 1], 0.f);
  float v2 = fmaxf(s.z + p.z + bias[c + 2], 0.f);
  float v3 = fmaxf(s.w + p.w + bias[c + 3], 0.f);
  uint2 o;
  o.x = pk2(v0, v1); o.y = pk2(v2, v3);
  *(uint2*)(outb + (size_t)i * 4) = o;
}

// ---------------- split-K reduce + bias + relu + dot(Wf3) -> out ----------------
__global__ __launch_bounds__(192) void reduce_final_kernel(
    const float* __restrict__ part, const float* __restrict__ bias,
    const float* __restrict__ Wf3, const float* __restrict__ bf3,
    float* __restrict__ out) {
  __shared__ float red[3];
  const int row = blockIdx.x;
  const int t = threadIdx.x;
  const int c = t * 4;
  const float* p0 = part + (size_t)row * kH + c;
  const float* p1 = p0 + (size_t)kB * kH;
  float4 a = *(const float4*)p0;
  float4 b = *(const float4*)p1;
  float v0 = fmaxf(a.x + b.x + bias[c], 0.f);
  float v1 = fmaxf(a.y + b.y + bias[c + 1], 0.f);
  float v2 = fmaxf(a.z + b.z + bias[c + 2], 0.f);
  float v3 = fmaxf(a.w + b.w + bias[c + 3], 0.f);
  float s = v0 * Wf3[c] + v1 * Wf3[c + 1] + v2 * Wf3[c + 2] + v3 * Wf3[c + 3];
#pragma unroll
  for (int off = 32; off; off >>= 1) s += __shfl_down(s, off);
  if ((t & 63) == 0) red[t >> 6] = s;
  __syncthreads();
  if (t == 0) out[row] = red[0] + red[1] + red[2] + bf3[0];
}

// ---------------- mega-kernel: transposes + input prep + wa1 + init(xb) ----------
struct TJobs {
  const float* in[6];
  __hip_bfloat16* out[6];
  int K[6];
  int N[6];
  int start[7];
};

__global__ __launch_bounds__(256) void transp_prep_kernel(
    TJobs j, const float* __restrict__ text_cls, const float* __restrict__ img_cls,
    __hip_bfloat16* __restrict__ text_bf, __hip_bfloat16* __restrict__ imgm_bf,
    int prep_blocks, const float* __restrict__ W1, const float* __restrict__ a_src,
    const float* __restrict__ a_dst, float* __restrict__ wa,
    int wa_blocks, uint4* __restrict__ xb4) {
  __shared__ float tl[32][33];
  const int bid = blockIdx.x;
  const int t = threadIdx.x;
  if (bid >= j.start[6] + prep_blocks + wa_blocks) {
    int i = (bid - j.start[6] - prep_blocks - wa_blocks) * 256 + t;
    if (i < kNN * kH * 2 / 16) xb4[i] = (uint4){0u, 0u, 0u, 0u};
    return;
  }
  if (bid >= j.start[6] + prep_blocks) {
    int gw = ((bid - j.start[6] - prep_blocks) * 256 + t) >> 6;
    int lane = t & 63;
    if (gw >= kHeads * kH) return;
    int i = gw >> 3, hd = gw & 7;
    const float* wrow = W1 + (size_t)i * (kHeads * kH) + hd * kH;
    const float* as = a_src + (size_t)hd * kH;
    const float* ad = a_dst + (size_t)hd * kH;
    float ss = 0.f, sd = 0.f;
    for (int c = lane; c < kH; c += 64) {
      float wv = wrow[c];
      ss = fmaf(wv, as[c], ss);
      sd = fmaf(wv, ad[c], sd);
    }
#pragma unroll
    for (int o = 32; o; o >>= 1) { ss += __shfl_down(ss, o); sd += __shfl_down(sd, o); }
    if (lane == 0) {
      wa[hd * kH + i] = ss;
      wa[kHeads * kH + hd * kH + i] = sd;
    }
    return;
  }
  if (bid >= j.start[6]) {
    int idx = (bid - j.start[6]) * 256 + t;
    if (idx < kB * kH) {
      text_bf[idx] = __float2bfloat16(text_cls[idx]);
      int b = idx / kH, c = idx - b * kH;
      const float* p = img_cls + (size_t)b * 3 * kH + c;
      imgm_bf[idx] = __float2bfloat16((p[0] + p[kH] + p[2 * kH]) * (1.f / 3.f));
    }
    return;
  }
  int idx = 0;
#pragma unroll
  for (int q = 1; q < 6; ++q)
    if (bid >= j.start[q]) idx = q;
  const int tile = bid - j.start[idx];
  const int N = j.N[idx], K = j.K[idx];
  const int tilesN = N >> 5;
  const int n0 = (tile % tilesN) << 5, k0 = (tile / tilesN) << 5;
  const float* in = j.in[idx];
  __hip_bfloat16* out = j.out[idx];
  const int r = t >> 3, c = (t & 7) * 4;
#pragma unroll
  for (int i = 0; i < 4; ++i) tl[r][c + i] = in[(size_t)(k0 + r) * N + n0 + c + i];
  __syncthreads();
  __hip_bfloat16* op = out + (size_t)(n0 + r) * K + k0 + c;
#pragma unroll
  for (int i = 0; i < 4; ++i) op[i] = __float2bfloat16(tl[c + i][r]);
}

// ---------------- s1: layer-1 scores from x (768-dim) ----------------
__global__ __launch_bounds__(256) void s1_kernel(const __hip_bfloat16* __restrict__ xb,
                                                 const float* __restrict__ wa,
                                                 float* __restrict__ s1s,
                                                 float* __restrict__ s1d) {
  __shared__ unsigned xrow[kH / 2];
  const int n = blockIdx.x;
  const int t = threadIdx.x;
  const unsigned* xp = (const unsigned*)(xb + (size_t)n * kH);
  if (t < 128) { xrow[t] = xp[t]; xrow[t + 128] = xp[t + 128]; xrow[t + 256] = xp[t + 256]; }
  __syncthreads();
  const int w = t >> 6, lane = t & 63;
  const float* ws0 = wa + (size_t)w * kH;
  const float* wd0 = wa + (size_t)(kHeads + w) * kH;
  const float* ws1 = wa + (size_t)(w + 4) * kH;
  const float* wd1 = wa + (size_t)(kHeads + w + 4) * kH;
  float s0 = 0.f, d0 = 0.f, s1 = 0.f, d1 = 0.f;
  for (int u = lane; u < kH / 2; u += 64) {
    unsigned v = xrow[u];
    float f0 = blo(v), f1 = bhi(v);
    int c = u * 2;
    s0 = fmaf(f0, ws0[c], fmaf(f1, ws0[c + 1], s0));
    d0 = fmaf(f0, wd0[c], fmaf(f1, wd0[c + 1], d0));
    s1 = fmaf(f0, ws1[c], fmaf(f1, ws1[c + 1], s1));
    d1 = fmaf(f0, wd1[c], fmaf(f1, wd1[c + 1], d1));
  }
#pragma unroll
  for (int o = 32; o; o >>= 1) {
    s0 += __shfl_down(s0, o); d0 += __shfl_down(d0, o);
    s1 += __shfl_down(s1, o); d1 += __shfl_down(d1, o);
  }
  if (lane == 0) {
    s1s[n * 8 + w] = s0;     s1d[n * 8 + w] = d0;
    s1s[n * 8 + w + 4] = s1; s1d[n * 8 + w + 4] = d1;
  }
}

// ---------------- layer-1 aggregation in x-space ----------------
__global__ __launch_bounds__(256) void agg1x_kernel(
    const int* __restrict__ rowptr, const int* __restrict__ cols,
    const float* __restrict__ s1s, const float* __restrict__ s1d,
    const __hip_bfloat16* __restrict__ xb, __hip_bfloat16* __restrict__ y) {
  __shared__ float mh[8], rdh[8], sdl[8];
  __shared__ float alph[128][9];
  const int n = blockIdx.x;
  const int t = threadIdx.x, w = t >> 6, lane = t & 63;
  const int beg = rowptr[n], end = rowptr[n + 1];
  if (t < 8) sdl[t] = s1d[n * 8 + t];
  __syncthreads();
#pragma unroll
  for (int p = 0; p < 2; ++p) {
    const int h = w + p * 4;
    const float sd = sdl[h];
    float m = -3.402823466e38f;
    for (int i = beg + lane; i < end; i += 64) {
      float e = s1s[(size_t)cols[i] * 8 + h] + sd;
      e = (e > 0.f) ? e : 0.2f * e;
      m = fmaxf(m, e);
    }
#pragma unroll
    for (int o = 32; o; o >>= 1) m = fmaxf(m, __shfl_xor(m, o));
    float ds = 0.f;
    for (int i = beg + lane; i < end; i += 64) {
      float e = s1s[(size_t)cols[i] * 8 + h] + sd;
      e = (e > 0.f) ? e : 0.2f * e;
      ds += expf(e - m);
    }
#pragma unroll
    for (int o = 32; o; o >>= 1) ds += __shfl_xor(ds, o);
    if (lane == 0) { mh[h] = m; rdh[h] = 1.f / (ds + 1e-16f); }
  }
  __syncthreads();

  float acc[8][4];
#pragma unroll
  for (int h = 0; h < 8; ++h)
#pragma unroll
    for (int q = 0; q < 4; ++q) acc[h][q] = 0.f;
  const int c0 = t * 4;

  for (int chunk = beg; chunk < end; chunk += 128) {
    const int cnt = min(128, end - chunk);
#pragma unroll
    for (int p = 0; p < 2; ++p) {
      const int h = w + p * 4;
      const float sd = sdl[h], m = mh[h], rd = rdh[h];
      for (int i = lane; i < cnt; i += 64) {
        float e = s1s[(size_t)cols[chunk + i] * 8 + h] + sd;
        e = (e > 0.f) ? e : 0.2f * e;
        alph[i][h] = expf(e - m) * rd;
      }
    }
    __syncthreads();
    if (t < 192) {
      for (int i = 0; i < cnt; ++i) {
        int src = cols[chunk + i];
        uint2 v = *(const uint2*)(xb + (size_t)src * kH + c0);
        float f0 = blo(v.x), f1 = bhi(v.x), f2 = blo(v.y), f3 = bhi(v.y);
#pragma unroll
        for (int h = 0; h < 8; ++h) {
          float a = alph[i][h];
          acc[h][0] = fmaf(a, f0, acc[h][0]);
          acc[h][1] = fmaf(a, f1, acc[h][1]);
          acc[h][2] = fmaf(a, f2, acc[h][2]);
          acc[h][3] = fmaf(a, f3, acc[h][3]);
        }
      }
    }
    __syncthreads();
  }
  if (t < 192) {
#pragma unroll
    for (int h = 0; h < 8; ++h) {
      uint2 o;
      o.x = pk2(acc[h][0], acc[h][1]);
      o.y = pk2(acc[h][2], acc[h][3]);
      *(uint2*)(y + ((size_t)n * 8 + h) * kH + c0) = o;
    }
  }
}

// ---------------- CSR: degrees (LDS atomics) + scan, one block ----------------
__global__ __launch_bounds__(1024) void scan_kernel(const int* __restrict__ ei,
                                                    int* __restrict__ rowptr,
                                                    int* __restrict__ cursor) {
  __shared__ int sdeg[kNN];
  __shared__ int sums[1024];
  int t = threadIdx.x;
#pragma unroll
  for (int i = 0; i < 3; ++i) sdeg[t * 3 + i] = 0;
  __syncthreads();
  for (int e = t; e < kET; e += 1024) {
    int dst = (e < kE) ? ei[kE + e] : (e - kE);
    atomicAdd(&sdeg[dst], 1);
  }
  __syncthreads();
  int v0 = sdeg[t * 3], v1 = sdeg[t * 3 + 1], v2 = sdeg[t * 3 + 2];
  int s = v0 + v1 + v2;
  sums[t] = s;
  __syncthreads();
  for (int o = 1; o < 1024; o <<= 1) {
    int xv = (t >= o) ? sums[t - o] : 0;
    __syncthreads();
    sums[t] += xv;
    __syncthreads();
  }
  int excl = sums[t] - s;
  rowptr[t * 3] = excl;          cursor[t * 3] = excl;
  rowptr[t * 3 + 1] = excl + v0; cursor[t * 3 + 1] = excl + v0;
  rowptr[t * 3 + 2] = excl + v0 + v1; cursor[t * 3 + 2] = excl + v0 + v1;
  if (t == 1023) rowptr[kNN] = excl + s;
}

// ---------------- fused: CSR fill + node-feature build (winner inline) ----------
constexpr int kFillBlocks = (kET + 255) / 256;

__global__ __launch_bounds__(256) void fill_build_kernel(
    const int* __restrict__ ei, int* __restrict__ cursor, int* __restrict__ cols,
    const int* __restrict__ user_idx, const float* __restrict__ user_table,
    const int* __restrict__ business_idx, const float* __restrict__ text_emb,
    const float* __restrict__ img_emb, const float* __restrict__ biz_feats,
    const float* __restrict__ W_bf, const float* __restrict__ b_bf,
    const float* __restrict__ biz_table, __hip_bfloat16* __restrict__ xb) {
  const int bid = blockIdx.x;
  if (bid < kFillBlocks) {
    int e = bid * 256 + threadIdx.x;
    if (e >= kET) return;
    int src, dst;
    if (e < kE) { src = ei[e]; dst = ei[kE + e]; } else { src = dst = e - kE; }
    int pos = atomicAdd(&cursor[dst], 1);
    cols[pos] = src;
    return;
  }
  const int b = bid - kFillBlocks;
  if (b < kNU) {
    int node = user_idx[b];
    for (int c = threadIdx.x; c < kH; c += 256)
      xb[(size_t)node * kH + c] = __float2bfloat16(user_table[(size_t)node * kH + c]);
  } else {
    const int m = b - kNU;
    // winner = last i with business_idx[i] == kNU + m (numpy last-wins)
    int cand = -1;
    for (int i = threadIdx.x; i < kB; i += 256)
      if (business_idx[i] == kNU + m) cand = i;  // i increases per thread
#pragma unroll
    for (int o = 32; o; o >>= 1) cand = max(cand, __shfl_xor(cand, o));
    __shared__ int red[4];
    if ((threadIdx.x & 63) == 0) red[threadIdx.x >> 6] = cand;
    __syncthreads();
    const int w = max(max(red[0], red[1]), max(red[2], red[3]));
    if (w < 0) return;
    int node = kNU + m;
    float f0 = biz_feats[w * 3], f1 = biz_feats[w * 3 + 1], f2 = biz_feats[w * 3 + 2];
    for (int c = threadIdx.x; c < kH; c += 256) {
      float meta = f0 * W_bf[c] + f1 * W_bf[kH + c] + f2 * W_bf[2 * kH + c] + b_bf[c];
      float v = (text_emb[(size_t)w * kH + c] + img_emb[(size_t)w * kH + c] + meta +
                 biz_table[(size_t)m * kH + c]) * 0.25f;
      xb[(size_t)node * kH + c] = __float2bfloat16(v);
    }
  }
}

// ---------------- GAT layer-2 segment softmax + aggregation ----------------
__global__ __launch_bounds__(256) void gat_agg_kernel(
    const int* __restrict__ rowptr, const int* __restrict__ cols,
    const float* __restrict__ s_src, const float* __restrict__ s_dst,
    const __hip_bfloat16* __restrict__ h, const float* __restrict__ bias,
    float* __restrict__ out_f, int total) {
  const int pair = blockIdx.x * 4 + (threadIdx.x >> 6);
  if (pair >= total) return;
  const int lane = threadIdx.x & 63;
  const int n = pair;
  const int beg = rowptr[n], end = rowptr[n + 1];
  const float sdv = s_dst[pair];

  float m = -3.402823466e38f;
  for (int i = beg + lane; i < end; i += 64) {
    float e = s_src[cols[i]] + sdv;
    e = (e > 0.f) ? e : 0.2f * e;
    m = fmaxf(m, e);
  }
#pragma unroll
  for (int o = 32; o; o >>= 1) m = fmaxf(m, __shfl_xor(m, o));

  float dsum = 0.f;
  for (int i = beg + lane; i < end; i += 64) {
    float e = s_src[cols[i]] + sdv;
    e = (e > 0.f) ? e : 0.2f * e;
    dsum += expf(e - m);
  }
#pragma unroll
  for (int o = 32; o; o >>= 1) dsum += __shfl_xor(dsum, o);
  const float rdsum = 1.f / (dsum + 1e-16f);

  float a[12];
#pragma unroll
  for (int q = 0; q < 12; ++q) a[q] = 0.f;
  const size_t hoff = (size_t)lane * 4;
  for (int i = beg; i < end; ++i) {
    int src = cols[i];
    float e = s_src[src] + sdv;
    e = (e > 0.f) ? e : 0.2f * e;
    float wgt = expf(e - m) * rdsum;
    const __hip_bfloat16* hp = h + (size_t)src * kH + hoff;
#pragma unroll
    for (int j = 0; j < 3; ++j) {
      uint2 v = *(const uint2*)(hp + j * 256);
      a[j * 4 + 0] = fmaf(wgt, blo(v.x), a[j * 4 + 0]);
      a[j * 4 + 1] = fmaf(wgt, bhi(v.x), a[j * 4 + 1]);
      a[j * 4 + 2] = fmaf(wgt, blo(v.y), a[j * 4 + 2]);
      a[j * 4 + 3] = fmaf(wgt, bhi(v.y), a[j * 4 + 3]);
    }
  }
  const size_t ob = (size_t)n * kH + hoff;
#pragma unroll
  for (int j = 0; j < 3; ++j) {
#pragma unroll
    for (int q = 0; q < 4; ++q)
      out_f[ob + j * 256 + q] = a[j * 4 + q] + bias[hoff + j * 256 + q];
  }
}

// ---------------- MLP head ----------------
__global__ void cat_kernel(const float* __restrict__ xf, const float* __restrict__ text_emb,
                           const float* __restrict__ img_emb, const int* __restrict__ user_idx,
                           const int* __restrict__ business_idx, __hip_bfloat16* __restrict__ cat) {
  int b = blockIdx.x;
  int u = user_idx[b], z = business_idx[b];
  __hip_bfloat16* crow = cat + (size_t)b * 4 * kH;
  for (int c = threadIdx.x; c < kH; c += blockDim.x) {
    crow[c] = __float2bfloat16(xf[(size_t)u * kH + c]);
    crow[kH + c] = __float2bfloat16(xf[(size_t)z * kH + c]);
    crow[2 * kH + c] = __float2bfloat16(text_emb[(size_t)b * kH + c]);
    crow[3 * kH + c] = __float2bfloat16(img_emb[(size_t)b * kH + c]);
  }
}

}  // namespace

extern "C" void kernel_launch(void* const* d_in, const int* in_sizes, int n_in,
                              void* d_out, int out_size, void* d_ws, size_t ws_size,
                              hipStream_t stream) {
  const float* text_cls = (const float*)d_in[0];
  const float* img_cls = (const float*)d_in[1];
  const float* biz_feats = (const float*)d_in[2];
  const float* W_text = (const float*)d_in[3];
  const float* b_text = (const float*)d_in[4];
  const float* W_img = (const float*)d_in[5];
  const float* b_img = (const float*)d_in[6];
  const float* W_bf = (const float*)d_in[7];
  const float* b_bf = (const float*)d_in[8];
  const float* user_table = (const float*)d_in[9];
  const float* biz_table = (const float*)d_in[10];
  const float* W1 = (const float*)d_in[11];
  const float* att_src1 = (const float*)d_in[12];
  const float* att_dst1 = (const float*)d_in[13];
  const float* b1 = (const float*)d_in[14];
  const float* W2 = (const float*)d_in[15];
  const float* att_src2 = (const float*)d_in[16];
  const float* att_dst2 = (const float*)d_in[17];
  const float* b2 = (const float*)d_in[18];
  const float* Wf1 = (const float*)d_in[19];
  const float* bf1 = (const float*)d_in[20];
  const float* Wf2 = (const float*)d_in[21];
  const float* bf2 = (const float*)d_in[22];
  const float* Wf3 = (const float*)d_in[23];
  const float* bf3 = (const float*)d_in[24];
  const int* user_idx = (const int*)d_in[25];
  const int* business_idx = (const int*)d_in[26];
  const int* edge_index = (const int*)d_in[27];
  float* out = (float*)d_out;
  (void)in_sizes; (void)n_in; (void)out_size; (void)ws_size;

  char* base = (char*)d_ws;
  size_t off = 0;
  auto alloc = [&](size_t bytes) -> void* {
    void* p = base + off;
    off = (off + bytes + 255) & ~(size_t)255;
    return p;
  };
  __hip_bfloat16* xb = (__hip_bfloat16*)alloc((size_t)kNN * kH * 2);
  __hip_bfloat16* text_bf = (__hip_bfloat16*)alloc((size_t)kB * kH * 2);
  __hip_bfloat16* imgm_bf = (__hip_bfloat16*)alloc((size_t)kB * kH * 2);
  float* text_emb = (float*)alloc((size_t)kB * kH * 4);
  float* img_emb = (float*)alloc((size_t)kB * kH * 4);
  __hip_bfloat16* Wtt = (__hip_bfloat16*)alloc((size_t)kH * kH * 2);
  __hip_bfloat16* Wit = (__hip_bfloat16*)alloc((size_t)kH * kH * 2);
  __hip_bfloat16* W1t = (__hip_bfloat16*)alloc((size_t)kHeads * kH * kH * 2);
  __hip_bfloat16* W2t = (__hip_bfloat16*)alloc((size_t)kH * kHeads * kH * 2);
  __hip_bfloat16* Wf1t = (__hip_bfloat16*)alloc((size_t)2 * kH * 4 * kH * 2);
  __hip_bfloat16* Wf2t = (__hip_bfloat16*)alloc((size_t)kH * 2 * kH * 2);
  float* wa = (float*)alloc((size_t)2 * kHeads * kH * 4);
  // union region: part (75.5MB, S=8 f32 partials) = [y 37.75MB][ext 37.75MB]
  // y: agg1x->gemm_head.  part: kpin->reduce_scores2.  ext hosts xf/catb/m1
  // (live only after part dies).  Wf partials reuse the y-subregion.
  __hip_bfloat16* y = (__hip_bfloat16*)alloc((size_t)kNN * kHeads * kH * 2);
  char* ext = (char*)alloc((size_t)kNN * kHeads * kH * 2);
  float* part = (float*)y;
  float* xf = (float*)ext;
  __hip_bfloat16* catb = (__hip_bfloat16*)(ext + 9437184);
  __hip_bfloat16* m1 = (__hip_bfloat16*)(ext + 9437184 + 6291456);
  __hip_bfloat16* x2 = (__hip_bfloat16*)alloc((size_t)kNN * kHeads * kH * 2);
  __hip_bfloat16* h2 = (__hip_bfloat16*)alloc((size_t)kNN * kH * 2);
  float* s1s = (float*)alloc((size_t)kNN * kHeads * 4);
  float* s1d = (float*)alloc((size_t)kNN * kHeads * 4);
  float* s2s = (float*)alloc((size_t)kNN * 4);
  float* s2d = (float*)alloc((size_t)kNN * 4);
  int* rowptr = (int*)alloc((size_t)(kNN + 1) * 4);
  int* cursor = (int*)alloc((size_t)kNN * 4);
  int* cols = (int*)alloc((size_t)kET * 4);

  // mega-kernel: weight transposes + input prep + wa1 + init(xb)
  TJobs tj;
  tj.in[0] = W_text; tj.out[0] = Wtt;  tj.K[0] = kH;          tj.N[0] = kH;
  tj.in[1] = W_img;  tj.out[1] = Wit;  tj.K[1] = kH;          tj.N[1] = kH;
  tj.in[2] = W1;     tj.out[2] = W1t;  tj.K[2] = kH;          tj.N[2] = kHeads * kH;
  tj.in[3] = W2;     tj.out[3] = W2t;  tj.K[3] = kHeads * kH; tj.N[3] = kH;
  tj.in[4] = Wf1;    tj.out[4] = Wf1t; tj.K[4] = 4 * kH;      tj.N[4] = 2 * kH;
  tj.in[5] = Wf2;    tj.out[5] = Wf2t; tj.K[5] = 2 * kH;      tj.N[5] = kH;
  tj.start[0] = 0;
  for (int q = 0; q < 6; ++q)
    tj.start[q + 1] = tj.start[q] + (tj.K[q] / 32) * (tj.N[q] / 32);
  const int prep_blocks = (kB * kH + 255) / 256;
  const int wa_blocks = (kHeads * kH) / 4;
  const int init_blocks = (kNN * kH * 2 / 16 + 255) / 256;
  transp_prep_kernel<<<tj.start[6] + prep_blocks + wa_blocks + init_blocks, 256, 0, stream>>>(
      tj, text_cls, img_cls, text_bf, imgm_bf, prep_blocks, W1, att_src1, att_dst1, wa,
      wa_blocks, (uint4*)xb);

  // encoders, batched in z
  mfma_gemm_dual<64, 128, 2, 4><<<dim3(kH / 128, kB / 64, 2), 256, 0, stream>>>(
      text_bf, Wtt, b_text, text_emb, imgm_bf, Wit, b_img, img_emb, kH, kH);

  // CSR degrees + scan (one block), then fused fill + node-feature build
  scan_kernel<<<1, 1024, 0, stream>>>(edge_index, rowptr, cursor);
  fill_build_kernel<<<kFillBlocks + kNN, 256, 0, stream>>>(
      edge_index, cursor, cols, user_idx, user_table, business_idx, text_emb, img_emb,
      biz_feats, W_bf, b_bf, biz_table, xb);

  // GAT layer 1, x-space: scores -> alpha-aggregate (768-dim) -> head-pinned GEMM
  s1_kernel<<<kNN, 256, 0, stream>>>(xb, wa, s1s, s1d);
  agg1x_kernel<<<kNN, 256, 0, stream>>>(rowptr, cols, s1s, s1d, xb, y);
  gemm_head<128, 128, 4, 4><<<dim3(kHeads, (kNN / 128) * (kH / 128)), 256, 0, stream>>>(
      y, W1t, b1, x2);

  // GAT layer 2: K-chunk->XCD-pinned split-K (S=8, 128^2), fused reduce+scores2
  mfma_gemm_kpin<128, 128, 4, 4, kS2>
      <<<dim3(kS2, (kNN / 128) * (kH / 128)), 256, 0, stream>>>(
          x2, W2t, part, kNN, kH, kHeads * kH);
  reduce_scores2_kernel<<<kNN, 192, 0, stream>>>(part, att_src2, att_dst2, h2, s2s, s2d);
  gat_agg_kernel<<<kNN / 4, 256, 0, stream>>>(rowptr, cols, s2s, s2d, h2, b2, xf, kNN);

  // MLP head: cat -> Wf1 (split-K S=2, partials in y-subregion) -> Wf2 -> fused final
  cat_kernel<<<kB, 256, 0, stream>>>(xf, text_emb, img_emb, user_idx, business_idx, catb);
  mfma_gemm_splitk<64, 128, 2, 4><<<dim3(2 * kH / 128, kB / 64, 2), 256, 0, stream>>>(
      catb, Wf1t, (float*)y, kB, 2 * kH, 4 * kH, 2 * kH);
  reduce_relu_kernel<<<(kB * 2 * kH / 4 + 255) / 256, 256, 0, stream>>>(
      (float*)y, bf1, m1, kB * 2 * kH / 4, 2 * kH);
  mfma_gemm_splitk<64, 128, 2, 4><<<dim3(kH / 128, kB / 64, 2), 256, 0, stream>>>(
      m1, Wf2t, (float*)y, kB, kH, 2 * kH, kH);
  reduce_final_kernel<<<kB, 192, 0, stream>>>((float*)y, bf2, Wf3, bf3, out);
}

// Round 11
// 255.748 us; speedup vs baseline: 1.0975x; 1.0975x over previous
//
#include <hip/hip_runtime.h>
#include <hip/hip_bf16.h>

namespace {

constexpr int kB = 1024;      // batch
constexpr int kNU = 1024;     // num users
constexpr int kNB = 2048;     // num businesses
constexpr int kNN = 3072;     // total nodes
constexpr int kE = 16384;     // raw edges
constexpr int kET = kE + kNN; // edges + self loops = 19456
constexpr int kH = 768;
constexpr int kHeads = 8;
constexpr int kS2 = 8;        // GAT2 split-K factor (XCD-pinned K-chunks)

typedef __attribute__((ext_vector_type(8))) short bf16x8_t;
typedef __attribute__((ext_vector_type(4))) float f32x4_t;

__device__ __forceinline__ float tof(float x) { return x; }
__device__ __forceinline__ float tof(__hip_bfloat16 x) { return __bfloat162float(x); }
__device__ __forceinline__ void stor(float* p, float v) { *p = v; }
__device__ __forceinline__ void stor(__hip_bfloat16* p, float v) { *p = __float2bfloat16(v); }

__device__ __forceinline__ float blo(unsigned u) {
  union { unsigned u; float f; } c; c.u = u << 16; return c.f;
}
__device__ __forceinline__ float bhi(unsigned u) {
  union { unsigned u; float f; } c; c.u = u & 0xffff0000u; return c.f;
}

__device__ __forceinline__ unsigned pk2(float a, float b) {
  union { __hip_bfloat16 h[2]; unsigned u; } c;
  c.h[0] = __float2bfloat16(a); c.h[1] = __float2bfloat16(b);
  return c.u;
}

__device__ __forceinline__ void gload_lds16(const void* g, void* l) {
  __builtin_amdgcn_global_load_lds(
      (const __attribute__((address_space(1))) void*)g,
      (__attribute__((address_space(3))) void*)l, 16, 0, 0);
}

// ---------------- 2-phase MFMA GEMM (proven r9 engine) with lda/ldc ----------------
template <int BM, int BN, int FM, int FN, typename TC>
__device__ __forceinline__ void gemm_body(
    const __hip_bfloat16* __restrict__ A, const __hip_bfloat16* __restrict__ Bt,
    const float* __restrict__ bias, TC* __restrict__ C,
    int K, int lda, int ldc, int act, int bx, int by) {
  __shared__ __align__(16) __hip_bfloat16 As[2][BM][32];
  __shared__ __align__(16) __hip_bfloat16 Bs[2][BN][32];
  const int t = threadIdx.x;
  const int w = t >> 6, lane = t & 63;
  const int wm = w >> 1, wn = w & 1;
  const int bm = by * BM, bn = bx * BN;
  const int lr = lane & 15, lg = lane >> 4;

  f32x4_t acc[FM][FN];
#pragma unroll
  for (int m = 0; m < FM; ++m)
#pragma unroll
    for (int n = 0; n < FN; ++n) acc[m][n] = (f32x4_t){0.f, 0.f, 0.f, 0.f};

  auto stage = [&](int buf, int kt) {
    const int k0 = kt << 5;
#pragma unroll
    for (int i = 0; i < BM / 64; ++i) {
      int L = i * 256 + t;
      gload_lds16(A + (size_t)(bm + (L >> 2)) * lda + k0 + (L & 3) * 8,
                  (char*)(&As[buf][0][0]) + ((size_t)(i * 256 + w * 64)) * 16);
    }
#pragma unroll
    for (int i = 0; i < BN / 64; ++i) {
      int L = i * 256 + t;
      gload_lds16(Bt + (size_t)(bn + (L >> 2)) * K + k0 + (L & 3) * 8,
                  (char*)(&Bs[buf][0][0]) + ((size_t)(i * 256 + w * 64)) * 16);
    }
  };

  const int NT = K >> 5;
  stage(0, 0);
  __syncthreads();
  for (int kt = 0; kt < NT; ++kt) {
    const int cur = kt & 1;
    if (kt + 1 < NT) stage(cur ^ 1, kt + 1);
    bf16x8_t af[FM], bv[FN];
#pragma unroll
    for (int m = 0; m < FM; ++m)
      af[m] = *(const bf16x8_t*)&As[cur][wm * FM * 16 + m * 16 + lr][lg * 8];
#pragma unroll
    for (int n = 0; n < FN; ++n)
      bv[n] = *(const bf16x8_t*)&Bs[cur][wn * FN * 16 + n * 16 + lr][lg * 8];
#pragma unroll
    for (int m = 0; m < FM; ++m)
#pragma unroll
      for (int n = 0; n < FN; ++n)
        acc[m][n] = __builtin_amdgcn_mfma_f32_16x16x32_bf16(af[m], bv[n], acc[m][n], 0, 0, 0);
    __syncthreads();
  }

#pragma unroll
  for (int m = 0; m < FM; ++m) {
    const int row0 = bm + wm * FM * 16 + m * 16 + lg * 4;
#pragma unroll
    for (int n = 0; n < FN; ++n) {
      const int cn = bn + wn * FN * 16 + n * 16 + lr;
      const float bvv = bias ? bias[cn] : 0.f;
#pragma unroll
      for (int r = 0; r < 4; ++r) {
        float v = acc[m][n][r] + bvv;
        if (act) v = fmaxf(v, 0.f);
        stor(&C[(size_t)(row0 + r) * ldc + cn], v);
      }
    }
  }
}

__device__ __forceinline__ void swz_xy(bool mfast, int& bx, int& by) {
  const int nwg = gridDim.x * gridDim.y;
  const int orig = blockIdx.y * gridDim.x + blockIdx.x;
  const int swz = (orig & 7) * (nwg >> 3) + (orig >> 3);
  if (mfast) { by = swz % gridDim.y; bx = swz / gridDim.y; }
  else       { bx = swz % gridDim.x; by = swz / gridDim.x; }
}

template <int BM, int BN, int FM, int FN>
__global__ __launch_bounds__(256) void mfma_gemm_dual(
    const __hip_bfloat16* __restrict__ A0, const __hip_bfloat16* __restrict__ Bt0,
    const float* __restrict__ bias0, float* __restrict__ C0,
    const __hip_bfloat16* __restrict__ A1, const __hip_bfloat16* __restrict__ Bt1,
    const float* __restrict__ bias1, float* __restrict__ C1,
    int N, int K) {
  int bx, by;
  swz_xy(true, bx, by);
  const __hip_bfloat16* A = blockIdx.z ? A1 : A0;
  const __hip_bfloat16* Bt = blockIdx.z ? Bt1 : Bt0;
  const float* bias = blockIdx.z ? bias1 : bias0;
  float* C = blockIdx.z ? C1 : C0;
  gemm_body<BM, BN, FM, FN, float>(A, Bt, bias, C, K, K, N, 0, bx, by);
}

// per-head projection, HEAD->XCD PINNED: blockIdx.x = head = dispatch%8 = XCD.
template <int BM, int BN, int FM, int FN>
__global__ __launch_bounds__(256) void gemm_head(
    const __hip_bfloat16* __restrict__ y, const __hip_bfloat16* __restrict__ W1t,
    const float* __restrict__ b1, __hip_bfloat16* __restrict__ x2) {
  const int hd = blockIdx.x;            // 0..7
  const int tile = blockIdx.y;          // 0..143
  const int bx = tile % (kH / BN);      // bx fastest: consecutive tiles share A panel
  const int by = tile / (kH / BN);
  gemm_body<BM, BN, FM, FN, __hip_bfloat16>(
      y + (size_t)hd * kH, W1t + (size_t)hd * kH * kH, b1 + hd * kH,
      x2 + (size_t)hd * kH, kH, kHeads * kH, kHeads * kH, 1, bx, by);
}

// split-K, K-CHUNK->XCD PINNED (2-phase engine, bf16 partials)
template <int BM, int BN, int FM, int FN, int S>
__global__ __launch_bounds__(256) void mfma_gemm_kpin(
    const __hip_bfloat16* __restrict__ A, const __hip_bfloat16* __restrict__ Bt,
    __hip_bfloat16* __restrict__ Cpart, int M, int N, int K) {
  __shared__ __align__(16) __hip_bfloat16 As[2][BM][32];
  __shared__ __align__(16) __hip_bfloat16 Bs[2][BN][32];
  const int kc = blockIdx.x;            // 0..S-1 -> XCD kc
  const int tile = blockIdx.y;
  const int tilesN = N / BN;
  const int bx = tile % tilesN;         // bx fastest: share A panel, sweep B
  const int by = tile / tilesN;
  const int KC = K / S;
  const int kbeg = kc * KC;
  const int t = threadIdx.x;
  const int w = t >> 6, lane = t & 63;
  const int wm = w >> 1, wn = w & 1;
  const int bm = by * BM, bn = bx * BN;
  const int lr = lane & 15, lg = lane >> 4;

  f32x4_t acc[FM][FN];
#pragma unroll
  for (int m = 0; m < FM; ++m)
#pragma unroll
    for (int n = 0; n < FN; ++n) acc[m][n] = (f32x4_t){0.f, 0.f, 0.f, 0.f};

  auto stage = [&](int buf, int kt) {
    const int k0 = kbeg + (kt << 5);
#pragma unroll
    for (int i = 0; i < BM / 64; ++i) {
      int L = i * 256 + t;
      gload_lds16(A + (size_t)(bm + (L >> 2)) * K + k0 + (L & 3) * 8,
                  (char*)(&As[buf][0][0]) + ((size_t)(i * 256 + w * 64)) * 16);
    }
#pragma unroll
    for (int i = 0; i < BN / 64; ++i) {
      int L = i * 256 + t;
      gload_lds16(Bt + (size_t)(bn + (L >> 2)) * K + k0 + (L & 3) * 8,
                  (char*)(&Bs[buf][0][0]) + ((size_t)(i * 256 + w * 64)) * 16);
    }
  };

  const int NT = KC >> 5;
  stage(0, 0);
  __syncthreads();
  for (int kt = 0; kt < NT; ++kt) {
    const int cur = kt & 1;
    if (kt + 1 < NT) stage(cur ^ 1, kt + 1);
    bf16x8_t af[FM], bv[FN];
#pragma unroll
    for (int m = 0; m < FM; ++m)
      af[m] = *(const bf16x8_t*)&As[cur][wm * FM * 16 + m * 16 + lr][lg * 8];
#pragma unroll
    for (int n = 0; n < FN; ++n)
      bv[n] = *(const bf16x8_t*)&Bs[cur][wn * FN * 16 + n * 16 + lr][lg * 8];
#pragma unroll
    for (int m = 0; m < FM; ++m)
#pragma unroll
      for (int n = 0; n < FN; ++n)
        acc[m][n] = __builtin_amdgcn_mfma_f32_16x16x32_bf16(af[m], bv[n], acc[m][n], 0, 0, 0);
    __syncthreads();
  }

  __hip_bfloat16* Cp = Cpart + (size_t)kc * M * N;
#pragma unroll
  for (int m = 0; m < FM; ++m) {
    const int row0 = bm + wm * FM * 16 + m * 16 + lg * 4;
#pragma unroll
    for (int n = 0; n < FN; ++n) {
      const int cn = bn + wn * FN * 16 + n * 16 + lr;
#pragma unroll
      for (int r = 0; r < 4; ++r)
        Cp[(size_t)(row0 + r) * N + cn] = __float2bfloat16(acc[m][n][r]);
    }
  }
}

// generic split-K (swizzled, 2-phase, f32 partials) for the MLP GEMMs
template <int BM, int BN, int FM, int FN>
__global__ __launch_bounds__(256) void mfma_gemm_splitk(
    const __hip_bfloat16* __restrict__ A, const __hip_bfloat16* __restrict__ Bt,
    float* __restrict__ Cpart, int M, int N, int K, int KC) {
  __shared__ __align__(16) __hip_bfloat16 As[2][BM][32];
  __shared__ __align__(16) __hip_bfloat16 Bs[2][BN][32];
  int bx, by;
  swz_xy(false, bx, by);
  const int t = threadIdx.x;
  const int w = t >> 6, lane = t & 63;
  const int wm = w >> 1, wn = w & 1;
  const int bm = by * BM, bn = bx * BN;
  const int kbeg = blockIdx.z * KC;
  const int lr = lane & 15, lg = lane >> 4;

  f32x4_t acc[FM][FN];
#pragma unroll
  for (int m = 0; m < FM; ++m)
#pragma unroll
    for (int n = 0; n < FN; ++n) acc[m][n] = (f32x4_t){0.f, 0.f, 0.f, 0.f};

  auto stage = [&](int buf, int kt) {
    const int k0 = kbeg + (kt << 5);
#pragma unroll
    for (int i = 0; i < BM / 64; ++i) {
      int L = i * 256 + t;
      gload_lds16(A + (size_t)(bm + (L >> 2)) * K + k0 + (L & 3) * 8,
                  (char*)(&As[buf][0][0]) + ((size_t)(i * 256 + w * 64)) * 16);
    }
#pragma unroll
    for (int i = 0; i < BN / 64; ++i) {
      int L = i * 256 + t;
      gload_lds16(Bt + (size_t)(bn + (L >> 2)) * K + k0 + (L & 3) * 8,
                  (char*)(&Bs[buf][0][0]) + ((size_t)(i * 256 + w * 64)) * 16);
    }
  };

  const int NT = KC >> 5;
  stage(0, 0);
  __syncthreads();
  for (int kt = 0; kt < NT; ++kt) {
    const int cur = kt & 1;
    if (kt + 1 < NT) stage(cur ^ 1, kt + 1);
    bf16x8_t af[FM], bv[FN];
#pragma unroll
    for (int m = 0; m < FM; ++m)
      af[m] = *(const bf16x8_t*)&As[cur][wm * FM * 16 + m * 16 + lr][lg * 8];
#pragma unroll
    for (int n = 0; n < FN; ++n)
      bv[n] = *(const bf16x8_t*)&Bs[cur][wn * FN * 16 + n * 16 + lr][lg * 8];
#pragma unroll
    for (int m = 0; m < FM; ++m)
#pragma unroll
      for (int n = 0; n < FN; ++n)
        acc[m][n] = __builtin_amdgcn_mfma_f32_16x16x32_bf16(af[m], bv[n], acc[m][n], 0, 0, 0);
    __syncthreads();
  }

  float* Cp = Cpart + (size_t)blockIdx.z * M * N;
#pragma unroll
  for (int m = 0; m < FM; ++m) {
    const int row0 = bm + wm * FM * 16 + m * 16 + lg * 4;
#pragma unroll
    for (int n = 0; n < FN; ++n) {
      const int cn = bn + wn * FN * 16 + n * 16 + lr;
#pragma unroll
      for (int r = 0; r < 4; ++r) Cp[(size_t)(row0 + r) * N + cn] = acc[m][n][r];
    }
  }
}

// ---------------- fused split-K reduce (S=8, bf16 partials) + scores2 ----------------
__global__ __launch_bounds__(192) void reduce_scores2_kernel(
    const __hip_bfloat16* __restrict__ part, const float* __restrict__ att_src,
    const float* __restrict__ att_dst, __hip_bfloat16* __restrict__ h2,
    float* __restrict__ s_src, float* __restrict__ s_dst) {
  __shared__ float redS[3], redD[3];
  const int row = blockIdx.x;
  const int t = threadIdx.x;
  const int c = t * 4;
  const __hip_bfloat16* p = part + (size_t)row * kH + c;
  float a0 = 0.f, a1 = 0.f, a2 = 0.f, a3 = 0.f;
#pragma unroll
  for (int z = 0; z < kS2; ++z) {
    uint2 v = *(const uint2*)(p + (size_t)z * kNN * kH);
    a0 += blo(v.x); a1 += bhi(v.x); a2 += blo(v.y); a3 += bhi(v.y);
  }
  __hip_bfloat16 b0 = __float2bfloat16(a0), b1 = __float2bfloat16(a1);
  __hip_bfloat16 b2 = __float2bfloat16(a2), b3 = __float2bfloat16(a3);
  __hip_bfloat16* o = h2 + (size_t)row * kH + c;
  o[0] = b0; o[1] = b1; o[2] = b2; o[3] = b3;
  float f0 = tof(b0), f1 = tof(b1), f2 = tof(b2), f3 = tof(b3);
  float ss = f0 * att_src[c] + f1 * att_src[c + 1] + f2 * att_src[c + 2] + f3 * att_src[c + 3];
  float sd = f0 * att_dst[c] + f1 * att_dst[c + 1] + f2 * att_dst[c + 2] + f3 * att_dst[c + 3];
#pragma unroll
  for (int off = 32; off; off >>= 1) { ss += __shfl_down(ss, off); sd += __shfl_down(sd, off); }
  if ((t & 63) == 0) { redS[t >> 6] = ss; redD[t >> 6] = sd; }
  __syncthreads();
  if (t == 0) {
    s_src[row] = redS[0] + redS[1] + redS[2];
    s_dst[row] = redD[0] + redD[1] + redD[2];
  }
}

// ---------------- split-K reduce + bias + relu -> bf16 (for Wf1) ----------------
__global__ void reduce_relu_kernel(const float* __restrict__ part,
                                   const float* __restrict__ bias,
                                   __hip_bfloat16* __restrict__ outb, int MN4, int N) {
  int i = blockIdx.x * 256 + threadIdx.x;
  if (i >= MN4) return;
  float4 s = ((const float4*)part)[i];
  float4 p = ((const float4*)part)[(size_t)MN4 + i];
  int c = (i * 4) % N;
  float v0 = fmaxf(s.x + p.x + bias[c], 0.f);
  float v1 = fmaxf(s.y + p.y + bias[c + 1], 0.f);
  float v2 = fmaxf(s.z + p.z + bias[c + 2], 0.f);
  float v3 = fmaxf(s.w + p.w + bias[c + 3], 0.f);
  uint2 o;
  o.x = pk2(v0, v1); o.y = pk2(v2, v3);
  *(uint2*)(outb + (size_t)i * 4) = o;
}

// ---------------- split-K reduce + bias + relu + dot(Wf3) -> out ----------------
__global__ __launch_bounds__(192) void reduce_final_kernel(
    const float* __restrict__ part, const float* __restrict__ bias,
    const float* __restrict__ Wf3, const float* __restrict__ bf3,
    float* __restrict__ out) {
  __shared__ float red[3];
  const int row = blockIdx.x;
  const int t = threadIdx.x;
  const int c = t * 4;
  const float* p0 = part + (size_t)row * kH + c;
  const float* p1 = p0 + (size_t)kB * kH;
  float4 a = *(const float4*)p0;
  float4 b = *(const float4*)p1;
  float v0 = fmaxf(a.x + b.x + bias[c], 0.f);
  float v1 = fmaxf(a.y + b.y + bias[c + 1], 0.f);
  float v2 = fmaxf(a.z + b.z + bias[c + 2], 0.f);
  float v3 = fmaxf(a.w + b.w + bias[c + 3], 0.f);
  float s = v0 * Wf3[c] + v1 * Wf3[c + 1] + v2 * Wf3[c + 2] + v3 * Wf3[c + 3];
#pragma unroll
  for (int off = 32; off; off >>= 1) s += __shfl_down(s, off);
  if ((t & 63) == 0) red[t >> 6] = s;
  __syncthreads();
  if (t == 0) out[row] = red[0] + red[1] + red[2] + bf3[0];
}

// ---------------- mega-kernel: transposes + input prep + wa1 + init(xb) ----------
struct TJobs {
  const float* in[6];
  __hip_bfloat16* out[6];
  int K[6];
  int N[6];
  int start[7];
};

__global__ __launch_bounds__(256) void transp_prep_kernel(
    TJobs j, const float* __restrict__ text_cls, const float* __restrict__ img_cls,
    __hip_bfloat16* __restrict__ text_bf, __hip_bfloat16* __restrict__ imgm_bf,
    int prep_blocks, const float* __restrict__ W1, const float* __restrict__ a_src,
    const float* __restrict__ a_dst, float* __restrict__ wa,
    int wa_blocks, uint4* __restrict__ xb4) {
  __shared__ float tl[32][33];
  const int bid = blockIdx.x;
  const int t = threadIdx.x;
  if (bid >= j.start[6] + prep_blocks + wa_blocks) {
    int i = (bid - j.start[6] - prep_blocks - wa_blocks) * 256 + t;
    if (i < kNN * kH * 2 / 16) xb4[i] = (uint4){0u, 0u, 0u, 0u};
    return;
  }
  if (bid >= j.start[6] + prep_blocks) {
    int gw = ((bid - j.start[6] - prep_blocks) * 256 + t) >> 6;
    int lane = t & 63;
    if (gw >= kHeads * kH) return;
    int i = gw >> 3, hd = gw & 7;
    const float* wrow = W1 + (size_t)i * (kHeads * kH) + hd * kH;
    const float* as = a_src + (size_t)hd * kH;
    const float* ad = a_dst + (size_t)hd * kH;
    float ss = 0.f, sd = 0.f;
    for (int c = lane; c < kH; c += 64) {
      float wv = wrow[c];
      ss = fmaf(wv, as[c], ss);
      sd = fmaf(wv, ad[c], sd);
    }
#pragma unroll
    for (int o = 32; o; o >>= 1) { ss += __shfl_down(ss, o); sd += __shfl_down(sd, o); }
    if (lane == 0) {
      wa[hd * kH + i] = ss;
      wa[kHeads * kH + hd * kH + i] = sd;
    }
    return;
  }
  if (bid >= j.start[6]) {
    int idx = (bid - j.start[6]) * 256 + t;
    if (idx < kB * kH) {
      text_bf[idx] = __float2bfloat16(text_cls[idx]);
      int b = idx / kH, c = idx - b * kH;
      const float* p = img_cls + (size_t)b * 3 * kH + c;
      imgm_bf[idx] = __float2bfloat16((p[0] + p[kH] + p[2 * kH]) * (1.f / 3.f));
    }
    return;
  }
  int idx = 0;
#pragma unroll
  for (int q = 1; q < 6; ++q)
    if (bid >= j.start[q]) idx = q;
  const int tile = bid - j.start[idx];
  const int N = j.N[idx], K = j.K[idx];
  const int tilesN = N >> 5;
  const int n0 = (tile % tilesN) << 5, k0 = (tile / tilesN) << 5;
  const float* in = j.in[idx];
  __hip_bfloat16* out = j.out[idx];
  const int r = t >> 3, c = (t & 7) * 4;
#pragma unroll
  for (int i = 0; i < 4; ++i) tl[r][c + i] = in[(size_t)(k0 + r) * N + n0 + c + i];
  __syncthreads();
  __hip_bfloat16* op = out + (size_t)(n0 + r) * K + k0 + c;
#pragma unroll
  for (int i = 0; i < 4; ++i) op[i] = __float2bfloat16(tl[c + i][r]);
}

// ---------------- s1: layer-1 scores from x (768-dim) ----------------
__global__ __launch_bounds__(256) void s1_kernel(const __hip_bfloat16* __restrict__ xb,
                                                 const float* __restrict__ wa,
                                                 float* __restrict__ s1s,
                                                 float* __restrict__ s1d) {
  __shared__ unsigned xrow[kH / 2];
  const int n = blockIdx.x;
  const int t = threadIdx.x;
  const unsigned* xp = (const unsigned*)(xb + (size_t)n * kH);
  if (t < 128) { xrow[t] = xp[t]; xrow[t + 128] = xp[t + 128]; xrow[t + 256] = xp[t + 256]; }
  __syncthreads();
  const int w = t >> 6, lane = t & 63;
  const float* ws0 = wa + (size_t)w * kH;
  const float* wd0 = wa + (size_t)(kHeads + w) * kH;
  const float* ws1 = wa + (size_t)(w + 4) * kH;
  const float* wd1 = wa + (size_t)(kHeads + w + 4) * kH;
  float s0 = 0.f, d0 = 0.f, s1 = 0.f, d1 = 0.f;
  for (int u = lane; u < kH / 2; u += 64) {
    unsigned v = xrow[u];
    float f0 = blo(v), f1 = bhi(v);
    int c = u * 2;
    s0 = fmaf(f0, ws0[c], fmaf(f1, ws0[c + 1], s0));
    d0 = fmaf(f0, wd0[c], fmaf(f1, wd0[c + 1], d0));
    s1 = fmaf(f0, ws1[c], fmaf(f1, ws1[c + 1], s1));
    d1 = fmaf(f0, wd1[c], fmaf(f1, wd1[c + 1], d1));
  }
#pragma unroll
  for (int o = 32; o; o >>= 1) {
    s0 += __shfl_down(s0, o); d0 += __shfl_down(d0, o);
    s1 += __shfl_down(s1, o); d1 += __shfl_down(d1, o);
  }
  if (lane == 0) {
    s1s[n * 8 + w] = s0;     s1d[n * 8 + w] = d0;
    s1s[n * 8 + w + 4] = s1; s1d[n * 8 + w + 4] = d1;
  }
}

// ---------------- layer-1 aggregation in x-space ----------------
__global__ __launch_bounds__(256) void agg1x_kernel(
    const int* __restrict__ rowptr, const int* __restrict__ cols,
    const float* __restrict__ s1s, const float* __restrict__ s1d,
    const __hip_bfloat16* __restrict__ xb, __hip_bfloat16* __restrict__ y) {
  __shared__ float mh[8], rdh[8], sdl[8];
  __shared__ float alph[128][9];
  const int n = blockIdx.x;
  const int t = threadIdx.x, w = t >> 6, lane = t & 63;
  const int beg = rowptr[n], end = rowptr[n + 1];
  if (t < 8) sdl[t] = s1d[n * 8 + t];
  __syncthreads();
#pragma unroll
  for (int p = 0; p < 2; ++p) {
    const int h = w + p * 4;
    const float sd = sdl[h];
    float m = -3.402823466e38f;
    for (int i = beg + lane; i < end; i += 64) {
      float e = s1s[(size_t)cols[i] * 8 + h] + sd;
      e = (e > 0.f) ? e : 0.2f * e;
      m = fmaxf(m, e);
    }
#pragma unroll
    for (int o = 32; o; o >>= 1) m = fmaxf(m, __shfl_xor(m, o));
    float ds = 0.f;
    for (int i = beg + lane; i < end; i += 64) {
      float e = s1s[(size_t)cols[i] * 8 + h] + sd;
      e = (e > 0.f) ? e : 0.2f * e;
      ds += expf(e - m);
    }
#pragma unroll
    for (int o = 32; o; o >>= 1) ds += __shfl_xor(ds, o);
    if (lane == 0) { mh[h] = m; rdh[h] = 1.f / (ds + 1e-16f); }
  }
  __syncthreads();

  float acc[8][4];
#pragma unroll
  for (int h = 0; h < 8; ++h)
#pragma unroll
    for (int q = 0; q < 4; ++q) acc[h][q] = 0.f;
  const int c0 = t * 4;

  for (int chunk = beg; chunk < end; chunk += 128) {
    const int cnt = min(128, end - chunk);
#pragma unroll
    for (int p = 0; p < 2; ++p) {
      const int h = w + p * 4;
      const float sd = sdl[h], m = mh[h], rd = rdh[h];
      for (int i = lane; i < cnt; i += 64) {
        float e = s1s[(size_t)cols[chunk + i] * 8 + h] + sd;
        e = (e > 0.f) ? e : 0.2f * e;
        alph[i][h] = expf(e - m) * rd;
      }
    }
    __syncthreads();
    if (t < 192) {
      for (int i = 0; i < cnt; ++i) {
        int src = cols[chunk + i];
        uint2 v = *(const uint2*)(xb + (size_t)src * kH + c0);
        float f0 = blo(v.x), f1 = bhi(v.x), f2 = blo(v.y), f3 = bhi(v.y);
#pragma unroll
        for (int h = 0; h < 8; ++h) {
          float a = alph[i][h];
          acc[h][0] = fmaf(a, f0, acc[h][0]);
          acc[h][1] = fmaf(a, f1, acc[h][1]);
          acc[h][2] = fmaf(a, f2, acc[h][2]);
          acc[h][3] = fmaf(a, f3, acc[h][3]);
        }
      }
    }
    __syncthreads();
  }
  if (t < 192) {
#pragma unroll
    for (int h = 0; h < 8; ++h) {
      uint2 o;
      o.x = pk2(acc[h][0], acc[h][1]);
      o.y = pk2(acc[h][2], acc[h][3]);
      *(uint2*)(y + ((size_t)n * 8 + h) * kH + c0) = o;
    }
  }
}

// ---------------- CSR: degrees (LDS atomics) + scan, one block ----------------
__global__ __launch_bounds__(1024) void scan_kernel(const int* __restrict__ ei,
                                                    int* __restrict__ rowptr,
                                                    int* __restrict__ cursor) {
  __shared__ int sdeg[kNN];
  __shared__ int sums[1024];
  int t = threadIdx.x;
#pragma unroll
  for (int i = 0; i < 3; ++i) sdeg[t * 3 + i] = 0;
  __syncthreads();
  for (int e = t; e < kET; e += 1024) {
    int dst = (e < kE) ? ei[kE + e] : (e - kE);
    atomicAdd(&sdeg[dst], 1);
  }
  __syncthreads();
  int v0 = sdeg[t * 3], v1 = sdeg[t * 3 + 1], v2 = sdeg[t * 3 + 2];
  int s = v0 + v1 + v2;
  sums[t] = s;
  __syncthreads();
  for (int o = 1; o < 1024; o <<= 1) {
    int xv = (t >= o) ? sums[t - o] : 0;
    __syncthreads();
    sums[t] += xv;
    __syncthreads();
  }
  int excl = sums[t] - s;
  rowptr[t * 3] = excl;          cursor[t * 3] = excl;
  rowptr[t * 3 + 1] = excl + v0; cursor[t * 3 + 1] = excl + v0;
  rowptr[t * 3 + 2] = excl + v0 + v1; cursor[t * 3 + 2] = excl + v0 + v1;
  if (t == 1023) rowptr[kNN] = excl + s;
}

// ---------------- fused: CSR fill + node-feature build (winner inline) ----------
constexpr int kFillBlocks = (kET + 255) / 256;

__global__ __launch_bounds__(256) void fill_build_kernel(
    const int* __restrict__ ei, int* __restrict__ cursor, int* __restrict__ cols,
    const int* __restrict__ user_idx, const float* __restrict__ user_table,
    const int* __restrict__ business_idx, const float* __restrict__ text_emb,
    const float* __restrict__ img_emb, const float* __restrict__ biz_feats,
    const float* __restrict__ W_bf, const float* __restrict__ b_bf,
    const float* __restrict__ biz_table, __hip_bfloat16* __restrict__ xb) {
  const int bid = blockIdx.x;
  if (bid < kFillBlocks) {
    int e = bid * 256 + threadIdx.x;
    if (e >= kET) return;
    int src, dst;
    if (e < kE) { src = ei[e]; dst = ei[kE + e]; } else { src = dst = e - kE; }
    int pos = atomicAdd(&cursor[dst], 1);
    cols[pos] = src;
    return;
  }
  const int b = bid - kFillBlocks;
  if (b < kNU) {
    int node = user_idx[b];
    for (int c = threadIdx.x; c < kH; c += 256)
      xb[(size_t)node * kH + c] = __float2bfloat16(user_table[(size_t)node * kH + c]);
  } else {
    const int m = b - kNU;
    // winner = last i with business_idx[i] == kNU + m (numpy last-wins)
    int cand = -1;
    for (int i = threadIdx.x; i < kB; i += 256)
      if (business_idx[i] == kNU + m) cand = i;
#pragma unroll
    for (int o = 32; o; o >>= 1) cand = max(cand, __shfl_xor(cand, o));
    __shared__ int red[4];
    if ((threadIdx.x & 63) == 0) red[threadIdx.x >> 6] = cand;
    __syncthreads();
    const int w = max(max(red[0], red[1]), max(red[2], red[3]));
    if (w < 0) return;
    int node = kNU + m;
    float f0 = biz_feats[w * 3], f1 = biz_feats[w * 3 + 1], f2 = biz_feats[w * 3 + 2];
    for (int c = threadIdx.x; c < kH; c += 256) {
      float meta = f0 * W_bf[c] + f1 * W_bf[kH + c] + f2 * W_bf[2 * kH + c] + b_bf[c];
      float v = (text_emb[(size_t)w * kH + c] + img_emb[(size_t)w * kH + c] + meta +
                 biz_table[(size_t)m * kH + c]) * 0.25f;
      xb[(size_t)node * kH + c] = __float2bfloat16(v);
    }
  }
}

// ---------------- GAT layer-2 segment softmax + aggregation ----------------
__global__ __launch_bounds__(256) void gat_agg_kernel(
    const int* __restrict__ rowptr, const int* __restrict__ cols,
    const float* __restrict__ s_src, const float* __restrict__ s_dst,
    const __hip_bfloat16* __restrict__ h, const float* __restrict__ bias,
    float* __restrict__ out_f, int total) {
  const int pair = blockIdx.x * 4 + (threadIdx.x >> 6);
  if (pair >= total) return;
  const int lane = threadIdx.x & 63;
  const int n = pair;
  const int beg = rowptr[n], end = rowptr[n + 1];
  const float sdv = s_dst[pair];

  float m = -3.402823466e38f;
  for (int i = beg + lane; i < end; i += 64) {
    float e = s_src[cols[i]] + sdv;
    e = (e > 0.f) ? e : 0.2f * e;
    m = fmaxf(m, e);
  }
#pragma unroll
  for (int o = 32; o; o >>= 1) m = fmaxf(m, __shfl_xor(m, o));

  float dsum = 0.f;
  for (int i = beg + lane; i < end; i += 64) {
    float e = s_src[cols[i]] + sdv;
    e = (e > 0.f) ? e : 0.2f * e;
    dsum += expf(e - m);
  }
#pragma unroll
  for (int o = 32; o; o >>= 1) dsum += __shfl_xor(dsum, o);
  const float rdsum = 1.f / (dsum + 1e-16f);

  float a[12];
#pragma unroll
  for (int q = 0; q < 12; ++q) a[q] = 0.f;
  const size_t hoff = (size_t)lane * 4;
  for (int i = beg; i < end; ++i) {
    int src = cols[i];
    float e = s_src[src] + sdv;
    e = (e > 0.f) ? e : 0.2f * e;
    float wgt = expf(e - m) * rdsum;
    const __hip_bfloat16* hp = h + (size_t)src * kH + hoff;
#pragma unroll
    for (int j = 0; j < 3; ++j) {
      uint2 v = *(const uint2*)(hp + j * 256);
      a[j * 4 + 0] = fmaf(wgt, blo(v.x), a[j * 4 + 0]);
      a[j * 4 + 1] = fmaf(wgt, bhi(v.x), a[j * 4 + 1]);
      a[j * 4 + 2] = fmaf(wgt, blo(v.y), a[j * 4 + 2]);
      a[j * 4 + 3] = fmaf(wgt, bhi(v.y), a[j * 4 + 3]);
    }
  }
  const size_t ob = (size_t)n * kH + hoff;
#pragma unroll
  for (int j = 0; j < 3; ++j) {
#pragma unroll
    for (int q = 0; q < 4; ++q)
      out_f[ob + j * 256 + q] = a[j * 4 + q] + bias[hoff + j * 256 + q];
  }
}

// ---------------- MLP head ----------------
__global__ void cat_kernel(const float* __restrict__ xf, const float* __restrict__ text_emb,
                           const float* __restrict__ img_emb, const int* __restrict__ user_idx,
                           const int* __restrict__ business_idx, __hip_bfloat16* __restrict__ cat) {
  int b = blockIdx.x;
  int u = user_idx[b], z = business_idx[b];
  __hip_bfloat16* crow = cat + (size_t)b * 4 * kH;
  for (int c = threadIdx.x; c < kH; c += blockDim.x) {
    crow[c] = __float2bfloat16(xf[(size_t)u * kH + c]);
    crow[kH + c] = __float2bfloat16(xf[(size_t)z * kH + c]);
    crow[2 * kH + c] = __float2bfloat16(text_emb[(size_t)b * kH + c]);
    crow[3 * kH + c] = __float2bfloat16(img_emb[(size_t)b * kH + c]);
  }
}

}  // namespace

extern "C" void kernel_launch(void* const* d_in, const int* in_sizes, int n_in,
                              void* d_out, int out_size, void* d_ws, size_t ws_size,
                              hipStream_t stream) {
  const float* text_cls = (const float*)d_in[0];
  const float* img_cls = (const float*)d_in[1];
  const float* biz_feats = (const float*)d_in[2];
  const float* W_text = (const float*)d_in[3];
  const float* b_text = (const float*)d_in[4];
  const float* W_img = (const float*)d_in[5];
  const float* b_img = (const float*)d_in[6];
  const float* W_bf = (const float*)d_in[7];
  const float* b_bf = (const float*)d_in[8];
  const float* user_table = (const float*)d_in[9];
  const float* biz_table = (const float*)d_in[10];
  const float* W1 = (const float*)d_in[11];
  const float* att_src1 = (const float*)d_in[12];
  const float* att_dst1 = (const float*)d_in[13];
  const float* b1 = (const float*)d_in[14];
  const float* W2 = (const float*)d_in[15];
  const float* att_src2 = (const float*)d_in[16];
  const float* att_dst2 = (const float*)d_in[17];
  const float* b2 = (const float*)d_in[18];
  const float* Wf1 = (const float*)d_in[19];
  const float* bf1 = (const float*)d_in[20];
  const float* Wf2 = (const float*)d_in[21];
  const float* bf2 = (const float*)d_in[22];
  const float* Wf3 = (const float*)d_in[23];
  const float* bf3 = (const float*)d_in[24];
  const int* user_idx = (const int*)d_in[25];
  const int* business_idx = (const int*)d_in[26];
  const int* edge_index = (const int*)d_in[27];
  float* out = (float*)d_out;
  (void)in_sizes; (void)n_in; (void)out_size; (void)ws_size;

  char* base = (char*)d_ws;
  size_t off = 0;
  auto alloc = [&](size_t bytes) -> void* {
    void* p = base + off;
    off = (off + bytes + 255) & ~(size_t)255;
    return p;
  };
  __hip_bfloat16* xb = (__hip_bfloat16*)alloc((size_t)kNN * kH * 2);
  __hip_bfloat16* text_bf = (__hip_bfloat16*)alloc((size_t)kB * kH * 2);
  __hip_bfloat16* imgm_bf = (__hip_bfloat16*)alloc((size_t)kB * kH * 2);
  float* text_emb = (float*)alloc((size_t)kB * kH * 4);
  float* img_emb = (float*)alloc((size_t)kB * kH * 4);
  __hip_bfloat16* Wtt = (__hip_bfloat16*)alloc((size_t)kH * kH * 2);
  __hip_bfloat16* Wit = (__hip_bfloat16*)alloc((size_t)kH * kH * 2);
  __hip_bfloat16* W1t = (__hip_bfloat16*)alloc((size_t)kHeads * kH * kH * 2);
  __hip_bfloat16* W2t = (__hip_bfloat16*)alloc((size_t)kH * kHeads * kH * 2);
  __hip_bfloat16* Wf1t = (__hip_bfloat16*)alloc((size_t)2 * kH * 4 * kH * 2);
  __hip_bfloat16* Wf2t = (__hip_bfloat16*)alloc((size_t)kH * 2 * kH * 2);
  float* wa = (float*)alloc((size_t)2 * kHeads * kH * 4);
  // y region (37.75MB): agg1x->gemm_head lifetime; later reused as
  //  - kpin bf16 partials (S=8, 8*kNN*kH*2B = 37.75MB exact fit)
  //  - Wf1/Wf2 f32 partials (<=12.6MB)
  __hip_bfloat16* y = (__hip_bfloat16*)alloc((size_t)kNN * kHeads * kH * 2);
  // ext region: xf/catb/m1 (live only after kpin partials are consumed... xf is
  // written by gat_agg AFTER reduce_scores2 consumed partials; disjoint from y)
  char* ext = (char*)alloc(9437184 + 6291456 + 3145728);
  __hip_bfloat16* part = (__hip_bfloat16*)y;
  float* xf = (float*)ext;
  __hip_bfloat16* catb = (__hip_bfloat16*)(ext + 9437184);
  __hip_bfloat16* m1 = (__hip_bfloat16*)(ext + 9437184 + 6291456);
  __hip_bfloat16* x2 = (__hip_bfloat16*)alloc((size_t)kNN * kHeads * kH * 2);
  __hip_bfloat16* h2 = (__hip_bfloat16*)alloc((size_t)kNN * kH * 2);
  float* s1s = (float*)alloc((size_t)kNN * kHeads * 4);
  float* s1d = (float*)alloc((size_t)kNN * kHeads * 4);
  float* s2s = (float*)alloc((size_t)kNN * 4);
  float* s2d = (float*)alloc((size_t)kNN * 4);
  int* rowptr = (int*)alloc((size_t)(kNN + 1) * 4);
  int* cursor = (int*)alloc((size_t)kNN * 4);
  int* cols = (int*)alloc((size_t)kET * 4);

  // mega-kernel: weight transposes + input prep + wa1 + init(xb)
  TJobs tj;
  tj.in[0] = W_text; tj.out[0] = Wtt;  tj.K[0] = kH;          tj.N[0] = kH;
  tj.in[1] = W_img;  tj.out[1] = Wit;  tj.K[1] = kH;          tj.N[1] = kH;
  tj.in[2] = W1;     tj.out[2] = W1t;  tj.K[2] = kH;          tj.N[2] = kHeads * kH;
  tj.in[3] = W2;     tj.out[3] = W2t;  tj.K[3] = kHeads * kH; tj.N[3] = kH;
  tj.in[4] = Wf1;    tj.out[4] = Wf1t; tj.K[4] = 4 * kH;      tj.N[4] = 2 * kH;
  tj.in[5] = Wf2;    tj.out[5] = Wf2t; tj.K[5] = 2 * kH;      tj.N[5] = kH;
  tj.start[0] = 0;
  for (int q = 0; q < 6; ++q)
    tj.start[q + 1] = tj.start[q] + (tj.K[q] / 32) * (tj.N[q] / 32);
  const int prep_blocks = (kB * kH + 255) / 256;
  const int wa_blocks = (kHeads * kH) / 4;
  const int init_blocks = (kNN * kH * 2 / 16 + 255) / 256;
  transp_prep_kernel<<<tj.start[6] + prep_blocks + wa_blocks + init_blocks, 256, 0, stream>>>(
      tj, text_cls, img_cls, text_bf, imgm_bf, prep_blocks, W1, att_src1, att_dst1, wa,
      wa_blocks, (uint4*)xb);

  // encoders, batched in z
  mfma_gemm_dual<64, 128, 2, 4><<<dim3(kH / 128, kB / 64, 2), 256, 0, stream>>>(
      text_bf, Wtt, b_text, text_emb, imgm_bf, Wit, b_img, img_emb, kH, kH);

  // CSR degrees + scan (one block), then fused fill + node-feature build
  scan_kernel<<<1, 1024, 0, stream>>>(edge_index, rowptr, cursor);
  fill_build_kernel<<<kFillBlocks + kNN, 256, 0, stream>>>(
      edge_index, cursor, cols, user_idx, user_table, business_idx, text_emb, img_emb,
      biz_feats, W_bf, b_bf, biz_table, xb);

  // GAT layer 1, x-space: scores -> alpha-aggregate (768-dim) -> head-pinned GEMM
  s1_kernel<<<kNN, 256, 0, stream>>>(xb, wa, s1s, s1d);
  agg1x_kernel<<<kNN, 256, 0, stream>>>(rowptr, cols, s1s, s1d, xb, y);
  gemm_head<128, 128, 4, 4><<<dim3(kHeads, (kNN / 128) * (kH / 128)), 256, 0, stream>>>(
      y, W1t, b1, x2);

  // GAT layer 2: K-chunk->XCD-pinned split-K (S=8, 128^2, bf16 partials),
  // fused reduce+scores2, aggregate
  mfma_gemm_kpin<128, 128, 4, 4, kS2>
      <<<dim3(kS2, (kNN / 128) * (kH / 128)), 256, 0, stream>>>(
          x2, W2t, part, kNN, kH, kHeads * kH);
  reduce_scores2_kernel<<<kNN, 192, 0, stream>>>(part, att_src2, att_dst2, h2, s2s, s2d);
  gat_agg_kernel<<<kNN / 4, 256, 0, stream>>>(rowptr, cols, s2s, s2d, h2, b2, xf, kNN);

  // MLP head: cat -> Wf1 (split-K S=2, f32 partials in y) -> Wf2 -> fused final
  cat_kernel<<<kB, 256, 0, stream>>>(xf, text_emb, img_emb, user_idx, business_idx, catb);
  mfma_gemm_splitk<64, 128, 2, 4><<<dim3(2 * kH / 128, kB / 64, 2), 256, 0, stream>>>(
      catb, Wf1t, (float*)y, kB, 2 * kH, 4 * kH, 2 * kH);
  reduce_relu_kernel<<<(kB * 2 * kH / 4 + 255) / 256, 256, 0, stream>>>(
      (float*)y, bf1, m1, kB * 2 * kH / 4, 2 * kH);
  mfma_gemm_splitk<64, 128, 2, 4><<<dim3(kH / 128, kB / 64, 2), 256, 0, stream>>>(
      m1, Wf2t, (float*)y, kB, kH, 2 * kH, kH);
  reduce_final_kernel<<<kB, 192, 0, stream>>>((float*)y, bf2, Wf3, bf3, out);
}

// Round 12
// 247.831 us; speedup vs baseline: 1.1326x; 1.0319x over previous
//
#include <hip/hip_runtime.h>
#include <hip/hip_bf16.h>

namespace {

constexpr int kB = 1024;      // batch
constexpr int kNU = 1024;     // num users
constexpr int kNB = 2048;     // num businesses
constexpr int kNN = 3072;     // total nodes
constexpr int kE = 16384;     // raw edges
constexpr int kET = kE + kNN; // edges + self loops = 19456
constexpr int kH = 768;
constexpr int kHeads = 8;
constexpr int kS2 = 8;        // GAT2 split-K factor (XCD-pinned K-chunks)

typedef __attribute__((ext_vector_type(8))) short bf16x8_t;
typedef __attribute__((ext_vector_type(4))) float f32x4_t;

__device__ __forceinline__ float tof(float x) { return x; }
__device__ __forceinline__ float tof(__hip_bfloat16 x) { return __bfloat162float(x); }
__device__ __forceinline__ void stor(float* p, float v) { *p = v; }
__device__ __forceinline__ void stor(__hip_bfloat16* p, float v) { *p = __float2bfloat16(v); }

__device__ __forceinline__ float blo(unsigned u) {
  union { unsigned u; float f; } c; c.u = u << 16; return c.f;
}
__device__ __forceinline__ float bhi(unsigned u) {
  union { unsigned u; float f; } c; c.u = u & 0xffff0000u; return c.f;
}

__device__ __forceinline__ unsigned pk2(float a, float b) {
  union { __hip_bfloat16 h[2]; unsigned u; } c;
  c.h[0] = __float2bfloat16(a); c.h[1] = __float2bfloat16(b);
  return c.u;
}

__device__ __forceinline__ void gload_lds16(const void* g, void* l) {
  __builtin_amdgcn_global_load_lds(
      (const __attribute__((address_space(1))) void*)g,
      (__attribute__((address_space(3))) void*)l, 16, 0, 0);
}

// ---------------- 2-phase MFMA GEMM (proven engine) with lda/ldc ----------------
template <int BM, int BN, int FM, int FN, typename TC>
__device__ __forceinline__ void gemm_body(
    const __hip_bfloat16* __restrict__ A, const __hip_bfloat16* __restrict__ Bt,
    const float* __restrict__ bias, TC* __restrict__ C,
    int K, int lda, int ldc, int act, int bx, int by) {
  __shared__ __align__(16) __hip_bfloat16 As[2][BM][32];
  __shared__ __align__(16) __hip_bfloat16 Bs[2][BN][32];
  const int t = threadIdx.x;
  const int w = t >> 6, lane = t & 63;
  const int wm = w >> 1, wn = w & 1;
  const int bm = by * BM, bn = bx * BN;
  const int lr = lane & 15, lg = lane >> 4;

  f32x4_t acc[FM][FN];
#pragma unroll
  for (int m = 0; m < FM; ++m)
#pragma unroll
    for (int n = 0; n < FN; ++n) acc[m][n] = (f32x4_t){0.f, 0.f, 0.f, 0.f};

  auto stage = [&](int buf, int kt) {
    const int k0 = kt << 5;
#pragma unroll
    for (int i = 0; i < BM / 64; ++i) {
      int L = i * 256 + t;
      gload_lds16(A + (size_t)(bm + (L >> 2)) * lda + k0 + (L & 3) * 8,
                  (char*)(&As[buf][0][0]) + ((size_t)(i * 256 + w * 64)) * 16);
    }
#pragma unroll
    for (int i = 0; i < BN / 64; ++i) {
      int L = i * 256 + t;
      gload_lds16(Bt + (size_t)(bn + (L >> 2)) * K + k0 + (L & 3) * 8,
                  (char*)(&Bs[buf][0][0]) + ((size_t)(i * 256 + w * 64)) * 16);
    }
  };

  const int NT = K >> 5;
  stage(0, 0);
  __syncthreads();
  for (int kt = 0; kt < NT; ++kt) {
    const int cur = kt & 1;
    if (kt + 1 < NT) stage(cur ^ 1, kt + 1);
    bf16x8_t af[FM], bv[FN];
#pragma unroll
    for (int m = 0; m < FM; ++m)
      af[m] = *(const bf16x8_t*)&As[cur][wm * FM * 16 + m * 16 + lr][lg * 8];
#pragma unroll
    for (int n = 0; n < FN; ++n)
      bv[n] = *(const bf16x8_t*)&Bs[cur][wn * FN * 16 + n * 16 + lr][lg * 8];
#pragma unroll
    for (int m = 0; m < FM; ++m)
#pragma unroll
      for (int n = 0; n < FN; ++n)
        acc[m][n] = __builtin_amdgcn_mfma_f32_16x16x32_bf16(af[m], bv[n], acc[m][n], 0, 0, 0);
    __syncthreads();
  }

#pragma unroll
  for (int m = 0; m < FM; ++m) {
    const int row0 = bm + wm * FM * 16 + m * 16 + lg * 4;
#pragma unroll
    for (int n = 0; n < FN; ++n) {
      const int cn = bn + wn * FN * 16 + n * 16 + lr;
      const float bvv = bias ? bias[cn] : 0.f;
#pragma unroll
      for (int r = 0; r < 4; ++r) {
        float v = acc[m][n][r] + bvv;
        if (act) v = fmaxf(v, 0.f);
        stor(&C[(size_t)(row0 + r) * ldc + cn], v);
      }
    }
  }
}

__device__ __forceinline__ void swz_xy(bool mfast, int& bx, int& by) {
  const int nwg = gridDim.x * gridDim.y;
  const int orig = blockIdx.y * gridDim.x + blockIdx.x;
  const int swz = (orig & 7) * (nwg >> 3) + (orig >> 3);
  if (mfast) { by = swz % gridDim.y; bx = swz / gridDim.y; }
  else       { bx = swz % gridDim.x; by = swz / gridDim.x; }
}

// per-head projection, HEAD->XCD PINNED: blockIdx.x = head = dispatch%8 = XCD.
template <int BM, int BN, int FM, int FN>
__global__ __launch_bounds__(256) void gemm_head(
    const __hip_bfloat16* __restrict__ y, const __hip_bfloat16* __restrict__ W1t,
    const float* __restrict__ b1, __hip_bfloat16* __restrict__ x2) {
  const int hd = blockIdx.x;            // 0..7
  const int tile = blockIdx.y;          // 0..143
  const int bx = tile % (kH / BN);      // bx fastest: consecutive tiles share A panel
  const int by = tile / (kH / BN);
  gemm_body<BM, BN, FM, FN, __hip_bfloat16>(
      y + (size_t)hd * kH, W1t + (size_t)hd * kH * kH, b1 + hd * kH,
      x2 + (size_t)hd * kH, kH, kHeads * kH, kHeads * kH, 1, bx, by);
}

// split-K, K-CHUNK->XCD PINNED (2-phase engine, bf16 partials)
template <int BM, int BN, int FM, int FN, int S>
__global__ __launch_bounds__(256) void mfma_gemm_kpin(
    const __hip_bfloat16* __restrict__ A, const __hip_bfloat16* __restrict__ Bt,
    __hip_bfloat16* __restrict__ Cpart, int M, int N, int K) {
  __shared__ __align__(16) __hip_bfloat16 As[2][BM][32];
  __shared__ __align__(16) __hip_bfloat16 Bs[2][BN][32];
  const int kc = blockIdx.x;            // 0..S-1 -> XCD kc
  const int tile = blockIdx.y;
  const int tilesN = N / BN;
  const int bx = tile % tilesN;         // bx fastest: share A panel, sweep B
  const int by = tile / tilesN;
  const int KC = K / S;
  const int kbeg = kc * KC;
  const int t = threadIdx.x;
  const int w = t >> 6, lane = t & 63;
  const int wm = w >> 1, wn = w & 1;
  const int bm = by * BM, bn = bx * BN;
  const int lr = lane & 15, lg = lane >> 4;

  f32x4_t acc[FM][FN];
#pragma unroll
  for (int m = 0; m < FM; ++m)
#pragma unroll
    for (int n = 0; n < FN; ++n) acc[m][n] = (f32x4_t){0.f, 0.f, 0.f, 0.f};

  auto stage = [&](int buf, int kt) {
    const int k0 = kbeg + (kt << 5);
#pragma unroll
    for (int i = 0; i < BM / 64; ++i) {
      int L = i * 256 + t;
      gload_lds16(A + (size_t)(bm + (L >> 2)) * K + k0 + (L & 3) * 8,
                  (char*)(&As[buf][0][0]) + ((size_t)(i * 256 + w * 64)) * 16);
    }
#pragma unroll
    for (int i = 0; i < BN / 64; ++i) {
      int L = i * 256 + t;
      gload_lds16(Bt + (size_t)(bn + (L >> 2)) * K + k0 + (L & 3) * 8,
                  (char*)(&Bs[buf][0][0]) + ((size_t)(i * 256 + w * 64)) * 16);
    }
  };

  const int NT = KC >> 5;
  stage(0, 0);
  __syncthreads();
  for (int kt = 0; kt < NT; ++kt) {
    const int cur = kt & 1;
    if (kt + 1 < NT) stage(cur ^ 1, kt + 1);
    bf16x8_t af[FM], bv[FN];
#pragma unroll
    for (int m = 0; m < FM; ++m)
      af[m] = *(const bf16x8_t*)&As[cur][wm * FM * 16 + m * 16 + lr][lg * 8];
#pragma unroll
    for (int n = 0; n < FN; ++n)
      bv[n] = *(const bf16x8_t*)&Bs[cur][wn * FN * 16 + n * 16 + lr][lg * 8];
#pragma unroll
    for (int m = 0; m < FM; ++m)
#pragma unroll
      for (int n = 0; n < FN; ++n)
        acc[m][n] = __builtin_amdgcn_mfma_f32_16x16x32_bf16(af[m], bv[n], acc[m][n], 0, 0, 0);
    __syncthreads();
  }

  __hip_bfloat16* Cp = Cpart + (size_t)kc * M * N;
#pragma unroll
  for (int m = 0; m < FM; ++m) {
    const int row0 = bm + wm * FM * 16 + m * 16 + lg * 4;
#pragma unroll
    for (int n = 0; n < FN; ++n) {
      const int cn = bn + wn * FN * 16 + n * 16 + lr;
#pragma unroll
      for (int r = 0; r < 4; ++r)
        Cp[(size_t)(row0 + r) * N + cn] = __float2bfloat16(acc[m][n][r]);
    }
  }
}

// generic split-K (swizzled, 2-phase, f32 partials) for the MLP GEMMs
template <int BM, int BN, int FM, int FN>
__global__ __launch_bounds__(256) void mfma_gemm_splitk(
    const __hip_bfloat16* __restrict__ A, const __hip_bfloat16* __restrict__ Bt,
    float* __restrict__ Cpart, int M, int N, int K, int KC) {
  __shared__ __align__(16) __hip_bfloat16 As[2][BM][32];
  __shared__ __align__(16) __hip_bfloat16 Bs[2][BN][32];
  int bx, by;
  swz_xy(false, bx, by);
  const int t = threadIdx.x;
  const int w = t >> 6, lane = t & 63;
  const int wm = w >> 1, wn = w & 1;
  const int bm = by * BM, bn = bx * BN;
  const int kbeg = blockIdx.z * KC;
  const int lr = lane & 15, lg = lane >> 4;

  f32x4_t acc[FM][FN];
#pragma unroll
  for (int m = 0; m < FM; ++m)
#pragma unroll
    for (int n = 0; n < FN; ++n) acc[m][n] = (f32x4_t){0.f, 0.f, 0.f, 0.f};

  auto stage = [&](int buf, int kt) {
    const int k0 = kbeg + (kt << 5);
#pragma unroll
    for (int i = 0; i < BM / 64; ++i) {
      int L = i * 256 + t;
      gload_lds16(A + (size_t)(bm + (L >> 2)) * K + k0 + (L & 3) * 8,
                  (char*)(&As[buf][0][0]) + ((size_t)(i * 256 + w * 64)) * 16);
    }
#pragma unroll
    for (int i = 0; i < BN / 64; ++i) {
      int L = i * 256 + t;
      gload_lds16(Bt + (size_t)(bn + (L >> 2)) * K + k0 + (L & 3) * 8,
                  (char*)(&Bs[buf][0][0]) + ((size_t)(i * 256 + w * 64)) * 16);
    }
  };

  const int NT = KC >> 5;
  stage(0, 0);
  __syncthreads();
  for (int kt = 0; kt < NT; ++kt) {
    const int cur = kt & 1;
    if (kt + 1 < NT) stage(cur ^ 1, kt + 1);
    bf16x8_t af[FM], bv[FN];
#pragma unroll
    for (int m = 0; m < FM; ++m)
      af[m] = *(const bf16x8_t*)&As[cur][wm * FM * 16 + m * 16 + lr][lg * 8];
#pragma unroll
    for (int n = 0; n < FN; ++n)
      bv[n] = *(const bf16x8_t*)&Bs[cur][wn * FN * 16 + n * 16 + lr][lg * 8];
#pragma unroll
    for (int m = 0; m < FM; ++m)
#pragma unroll
      for (int n = 0; n < FN; ++n)
        acc[m][n] = __builtin_amdgcn_mfma_f32_16x16x32_bf16(af[m], bv[n], acc[m][n], 0, 0, 0);
    __syncthreads();
  }

  float* Cp = Cpart + (size_t)blockIdx.z * M * N;
#pragma unroll
  for (int m = 0; m < FM; ++m) {
    const int row0 = bm + wm * FM * 16 + m * 16 + lg * 4;
#pragma unroll
    for (int n = 0; n < FN; ++n) {
      const int cn = bn + wn * FN * 16 + n * 16 + lr;
#pragma unroll
      for (int r = 0; r < 4; ++r) Cp[(size_t)(row0 + r) * N + cn] = acc[m][n][r];
    }
  }
}

// ---------------- fused split-K reduce (S=8, bf16 partials) + scores2 ----------------
__global__ __launch_bounds__(192) void reduce_scores2_kernel(
    const __hip_bfloat16* __restrict__ part, const float* __restrict__ att_src,
    const float* __restrict__ att_dst, __hip_bfloat16* __restrict__ h2,
    float* __restrict__ s_src, float* __restrict__ s_dst) {
  __shared__ float redS[3], redD[3];
  const int row = blockIdx.x;
  const int t = threadIdx.x;
  const int c = t * 4;
  const __hip_bfloat16* p = part + (size_t)row * kH + c;
  float a0 = 0.f, a1 = 0.f, a2 = 0.f, a3 = 0.f;
#pragma unroll
  for (int z = 0; z < kS2; ++z) {
    uint2 v = *(const uint2*)(p + (size_t)z * kNN * kH);
    a0 += blo(v.x); a1 += bhi(v.x); a2 += blo(v.y); a3 += bhi(v.y);
  }
  __hip_bfloat16 b0 = __float2bfloat16(a0), b1 = __float2bfloat16(a1);
  __hip_bfloat16 b2 = __float2bfloat16(a2), b3 = __float2bfloat16(a3);
  __hip_bfloat16* o = h2 + (size_t)row * kH + c;
  o[0] = b0; o[1] = b1; o[2] = b2; o[3] = b3;
  float f0 = tof(b0), f1 = tof(b1), f2 = tof(b2), f3 = tof(b3);
  float ss = f0 * att_src[c] + f1 * att_src[c + 1] + f2 * att_src[c + 2] + f3 * att_src[c + 3];
  float sd = f0 * att_dst[c] + f1 * att_dst[c + 1] + f2 * att_dst[c + 2] + f3 * att_dst[c + 3];
#pragma unroll
  for (int off = 32; off; off >>= 1) { ss += __shfl_down(ss, off); sd += __shfl_down(sd, off); }
  if ((t & 63) == 0) { redS[t >> 6] = ss; redD[t >> 6] = sd; }
  __syncthreads();
  if (t == 0) {
    s_src[row] = redS[0] + redS[1] + redS[2];
    s_dst[row] = redD[0] + redD[1] + redD[2];
  }
}

// ---------------- split-K reduce + bias + relu -> bf16 (for Wf1) ----------------
__global__ void reduce_relu_kernel(const float* __restrict__ part,
                                   const float* __restrict__ bias,
                                   __hip_bfloat16* __restrict__ outb, int MN4, int N) {
  int i = blockIdx.x * 256 + threadIdx.x;
  if (i >= MN4) return;
  float4 s = ((const float4*)part)[i];
  float4 p = ((const float4*)part)[(size_t)MN4 + i];
  int c = (i * 4) % N;
  float v0 = fmaxf(s.x + p.x + bias[c], 0.f);
  float v1 = fmaxf(s.y + p.y + bias[c + 1], 0.f);
  float v2 = fmaxf(s.z + p.z + bias[c + 2], 0.f);
  float v3 = fmaxf(s.w + p.w + bias[c + 3], 0.f);
  uint2 o;
  o.x = pk2(v0, v1); o.y = pk2(v2, v3);
  *(uint2*)(outb + (size_t)i * 4) = o;
}

// ---------------- split-K reduce + bias + relu + dot(Wf3) -> out ----------------
__global__ __launch_bounds__(192) void reduce_final_kernel(
    const float* __restrict__ part, const float* __restrict__ bias,
    const float* __restrict__ Wf3, const float* __restrict__ bf3,
    float* __restrict__ out) {
  __shared__ float red[3];
  const int row = blockIdx.x;
  const int t = threadIdx.x;
  const int c = t * 4;
  const float* p0 = part + (size_t)row * kH + c;
  const float* p1 = p0 + (size_t)kB * kH;
  float4 a = *(const float4*)p0;
  float4 b = *(const float4*)p1;
  float v0 = fmaxf(a.x + b.x + bias[c], 0.f);
  float v1 = fmaxf(a.y + b.y + bias[c + 1], 0.f);
  float v2 = fmaxf(a.z + b.z + bias[c + 2], 0.f);
  float v3 = fmaxf(a.w + b.w + bias[c + 3], 0.f);
  float s = v0 * Wf3[c] + v1 * Wf3[c + 1] + v2 * Wf3[c + 2] + v3 * Wf3[c + 3];
#pragma unroll
  for (int off = 32; off; off >>= 1) s += __shfl_down(s, off);
  if ((t & 63) == 0) red[t >> 6] = s;
  __syncthreads();
  if (t == 0) out[row] = red[0] + red[1] + red[2] + bf3[0];
}

// ---------------- per-node attention-score dots (heads via waves) ----------------
__device__ __forceinline__ void node_scores(const float* xrow, int node,
                                            const float* __restrict__ wa,
                                            float* __restrict__ s1s,
                                            float* __restrict__ s1d, int t) {
  const int w = t >> 6, lane = t & 63;
  const float* ws0 = wa + (size_t)w * kH;
  const float* wd0 = wa + (size_t)(kHeads + w) * kH;
  const float* ws1 = wa + (size_t)(w + 4) * kH;
  const float* wd1 = wa + (size_t)(kHeads + w + 4) * kH;
  float s0 = 0.f, d0 = 0.f, s1v = 0.f, d1 = 0.f;
  for (int c = lane; c < kH; c += 64) {
    float f = xrow[c];
    s0 = fmaf(f, ws0[c], s0);
    d0 = fmaf(f, wd0[c], d0);
    s1v = fmaf(f, ws1[c], s1v);
    d1 = fmaf(f, wd1[c], d1);
  }
#pragma unroll
  for (int o = 32; o; o >>= 1) {
    s0 += __shfl_down(s0, o); d0 += __shfl_down(d0, o);
    s1v += __shfl_down(s1v, o); d1 += __shfl_down(d1, o);
  }
  if (lane == 0) {
    s1s[node * 8 + w] = s0;      s1d[node * 8 + w] = d0;
    s1s[node * 8 + w + 4] = s1v; s1d[node * 8 + w + 4] = d1;
  }
}

// ---------------- mega1: transposes + prep + wa1 + init + CSR scan ----------------
struct TJobs {
  const float* in[6];
  __hip_bfloat16* out[6];
  int K[6];
  int N[6];
  int start[7];
};

__global__ __launch_bounds__(256) void mega1_kernel(
    TJobs j, const float* __restrict__ text_cls, const float* __restrict__ img_cls,
    __hip_bfloat16* __restrict__ text_bf, __hip_bfloat16* __restrict__ imgm_bf,
    int prep_blocks, const float* __restrict__ W1, const float* __restrict__ a_src,
    const float* __restrict__ a_dst, float* __restrict__ wa,
    int wa_blocks, uint4* __restrict__ xb4, uint4* __restrict__ s1sd4,
    const int* __restrict__ ei, int* __restrict__ rowptr, int* __restrict__ cursor) {
  __shared__ float tl[32][33];
  __shared__ int sdeg[kNN];
  __shared__ int ssum[256];
  const int bid = blockIdx.x;
  const int t = threadIdx.x;
  if (bid == 0) {
    // CSR degree + scan, 256 threads (each owns 12 nodes)
    for (int i = t; i < kNN; i += 256) sdeg[i] = 0;
    __syncthreads();
    for (int e = t; e < kET; e += 256) {
      int dst = (e < kE) ? ei[kE + e] : (e - kE);
      atomicAdd(&sdeg[dst], 1);
    }
    __syncthreads();
    int loc[12];
    int s = 0;
#pragma unroll
    for (int q = 0; q < 12; ++q) { loc[q] = sdeg[t * 12 + q]; s += loc[q]; }
    ssum[t] = s;
    __syncthreads();
    for (int o = 1; o < 256; o <<= 1) {
      int xv = (t >= o) ? ssum[t - o] : 0;
      __syncthreads();
      ssum[t] += xv;
      __syncthreads();
    }
    int excl = ssum[t] - s;
#pragma unroll
    for (int q = 0; q < 12; ++q) {
      rowptr[t * 12 + q] = excl;
      cursor[t * 12 + q] = excl;
      excl += loc[q];
    }
    if (t == 255) rowptr[kNN] = excl;
    return;
  }
  const int b2 = bid - 1;
  if (b2 >= j.start[6] + prep_blocks + wa_blocks) {
    // init region: zero xb + s1s/s1d
    int i = (b2 - j.start[6] - prep_blocks - wa_blocks) * 256 + t;
    if (i < kNN * kH * 2 / 16) xb4[i] = (uint4){0u, 0u, 0u, 0u};
    if (i < 2 * kNN * kHeads * 4 / 16) s1sd4[i] = (uint4){0u, 0u, 0u, 0u};
    return;
  }
  if (b2 >= j.start[6] + prep_blocks) {
    // wa1 region
    int gw = ((b2 - j.start[6] - prep_blocks) * 256 + t) >> 6;
    int lane = t & 63;
    if (gw >= kHeads * kH) return;
    int i = gw >> 3, hd = gw & 7;
    const float* wrow = W1 + (size_t)i * (kHeads * kH) + hd * kH;
    const float* as = a_src + (size_t)hd * kH;
    const float* ad = a_dst + (size_t)hd * kH;
    float ss = 0.f, sd = 0.f;
    for (int c = lane; c < kH; c += 64) {
      float wv = wrow[c];
      ss = fmaf(wv, as[c], ss);
      sd = fmaf(wv, ad[c], sd);
    }
#pragma unroll
    for (int o = 32; o; o >>= 1) { ss += __shfl_down(ss, o); sd += __shfl_down(sd, o); }
    if (lane == 0) {
      wa[hd * kH + i] = ss;
      wa[kHeads * kH + hd * kH + i] = sd;
    }
    return;
  }
  if (b2 >= j.start[6]) {
    int idx = (b2 - j.start[6]) * 256 + t;
    if (idx < kB * kH) {
      text_bf[idx] = __float2bfloat16(text_cls[idx]);
      int b = idx / kH, c = idx - b * kH;
      const float* p = img_cls + (size_t)b * 3 * kH + c;
      imgm_bf[idx] = __float2bfloat16((p[0] + p[kH] + p[2 * kH]) * (1.f / 3.f));
    }
    return;
  }
  int idx = 0;
#pragma unroll
  for (int q = 1; q < 6; ++q)
    if (b2 >= j.start[q]) idx = q;
  const int tile = b2 - j.start[idx];
  const int N = j.N[idx], K = j.K[idx];
  const int tilesN = N >> 5;
  const int n0 = (tile % tilesN) << 5, k0 = (tile / tilesN) << 5;
  const float* in = j.in[idx];
  __hip_bfloat16* out = j.out[idx];
  const int r = t >> 3, c = (t & 7) * 4;
#pragma unroll
  for (int i = 0; i < 4; ++i) tl[r][c + i] = in[(size_t)(k0 + r) * N + n0 + c + i];
  __syncthreads();
  __hip_bfloat16* op = out + (size_t)(n0 + r) * K + k0 + c;
#pragma unroll
  for (int i = 0; i < 4; ++i) op[i] = __float2bfloat16(tl[c + i][r]);
}

// ---------------- mega2: encoder GEMMs + CSR fill + build_user(+scores) ------------
constexpr int kEncBlocks = (kH / 128) * (kB / 64);     // 96 per problem
constexpr int kFillBlocks = (kET + 255) / 256;         // 76

__global__ __launch_bounds__(256) void mega2_kernel(
    const __hip_bfloat16* __restrict__ text_bf, const __hip_bfloat16* __restrict__ Wtt,
    const float* __restrict__ b_text, float* __restrict__ text_emb,
    const __hip_bfloat16* __restrict__ imgm_bf, const __hip_bfloat16* __restrict__ Wit,
    const float* __restrict__ b_img, float* __restrict__ img_emb,
    const int* __restrict__ ei, int* __restrict__ cursor, int* __restrict__ cols,
    const int* __restrict__ user_idx, const float* __restrict__ user_table,
    const float* __restrict__ wa, __hip_bfloat16* __restrict__ xb,
    float* __restrict__ s1s, float* __restrict__ s1d) {
  __shared__ float xrow[kH];
  const int bid = blockIdx.x;
  const int t = threadIdx.x;
  if (bid < 2 * kEncBlocks) {
    const int p = bid / kEncBlocks, tile = bid % kEncBlocks;
    const int bx = tile % (kH / 128), by = tile / (kH / 128);
    const __hip_bfloat16* A = p ? imgm_bf : text_bf;
    const __hip_bfloat16* Bt = p ? Wit : Wtt;
    const float* bias = p ? b_img : b_text;
    float* C = p ? img_emb : text_emb;
    gemm_body<64, 128, 2, 4, float>(A, Bt, bias, C, kH, kH, kH, 0, bx, by);
    return;
  }
  if (bid < 2 * kEncBlocks + kFillBlocks) {
    int e = (bid - 2 * kEncBlocks) * 256 + t;
    if (e >= kET) return;
    int src, dst;
    if (e < kE) { src = ei[e]; dst = ei[kE + e]; } else { src = dst = e - kE; }
    int pos = atomicAdd(&cursor[dst], 1);
    cols[pos] = src;
    return;
  }
  // build_user + scores
  const int b = bid - 2 * kEncBlocks - kFillBlocks;
  const int node = user_idx[b];
  for (int c = t; c < kH; c += 256) {
    __hip_bfloat16 bf = __float2bfloat16(user_table[(size_t)node * kH + c]);
    xb[(size_t)node * kH + c] = bf;
    xrow[c] = tof(bf);
  }
  __syncthreads();
  node_scores(xrow, node, wa, s1s, s1d, t);
}

// ---------------- mega3: build_biz (winner inline) + scores ----------------
__global__ __launch_bounds__(256) void mega3_kernel(
    const int* __restrict__ business_idx, const float* __restrict__ text_emb,
    const float* __restrict__ img_emb, const float* __restrict__ biz_feats,
    const float* __restrict__ W_bf, const float* __restrict__ b_bf,
    const float* __restrict__ biz_table, const float* __restrict__ wa,
    __hip_bfloat16* __restrict__ xb, float* __restrict__ s1s, float* __restrict__ s1d) {
  __shared__ int red[4];
  __shared__ float xrow[kH];
  const int m = blockIdx.x;
  const int t = threadIdx.x;
  int cand = -1;
  for (int i = t; i < kB; i += 256)
    if (business_idx[i] == kNU + m) cand = i;  // per-thread last match
#pragma unroll
  for (int o = 32; o; o >>= 1) cand = max(cand, __shfl_xor(cand, o));
  if ((t & 63) == 0) red[t >> 6] = cand;
  __syncthreads();
  const int w = max(max(red[0], red[1]), max(red[2], red[3]));
  if (w < 0) return;  // zero row + zero scores (from init) = reference semantics
  const int node = kNU + m;
  float f0 = biz_feats[w * 3], f1 = biz_feats[w * 3 + 1], f2 = biz_feats[w * 3 + 2];
  for (int c = t; c < kH; c += 256) {
    float meta = f0 * W_bf[c] + f1 * W_bf[kH + c] + f2 * W_bf[2 * kH + c] + b_bf[c];
    float v = (text_emb[(size_t)w * kH + c] + img_emb[(size_t)w * kH + c] + meta +
               biz_table[(size_t)m * kH + c]) * 0.25f;
    __hip_bfloat16 bf = __float2bfloat16(v);
    xb[(size_t)node * kH + c] = bf;
    xrow[c] = tof(bf);
  }
  __syncthreads();
  node_scores(xrow, node, wa, s1s, s1d, t);
}

// ---------------- layer-1 aggregation in x-space ----------------
__global__ __launch_bounds__(256) void agg1x_kernel(
    const int* __restrict__ rowptr, const int* __restrict__ cols,
    const float* __restrict__ s1s, const float* __restrict__ s1d,
    const __hip_bfloat16* __restrict__ xb, __hip_bfloat16* __restrict__ y) {
  __shared__ float mh[8], rdh[8], sdl[8];
  __shared__ float alph[128][9];
  const int n = blockIdx.x;
  const int t = threadIdx.x, w = t >> 6, lane = t & 63;
  const int beg = rowptr[n], end = rowptr[n + 1];
  if (t < 8) sdl[t] = s1d[n * 8 + t];
  __syncthreads();
#pragma unroll
  for (int p = 0; p < 2; ++p) {
    const int h = w + p * 4;
    const float sd = sdl[h];
    float m = -3.402823466e38f;
    for (int i = beg + lane; i < end; i += 64) {
      float e = s1s[(size_t)cols[i] * 8 + h] + sd;
      e = (e > 0.f) ? e : 0.2f * e;
      m = fmaxf(m, e);
    }
#pragma unroll
    for (int o = 32; o; o >>= 1) m = fmaxf(m, __shfl_xor(m, o));
    float ds = 0.f;
    for (int i = beg + lane; i < end; i += 64) {
      float e = s1s[(size_t)cols[i] * 8 + h] + sd;
      e = (e > 0.f) ? e : 0.2f * e;
      ds += expf(e - m);
    }
#pragma unroll
    for (int o = 32; o; o >>= 1) ds += __shfl_xor(ds, o);
    if (lane == 0) { mh[h] = m; rdh[h] = 1.f / (ds + 1e-16f); }
  }
  __syncthreads();

  float acc[8][4];
#pragma unroll
  for (int h = 0; h < 8; ++h)
#pragma unroll
    for (int q = 0; q < 4; ++q) acc[h][q] = 0.f;
  const int c0 = t * 4;

  for (int chunk = beg; chunk < end; chunk += 128) {
    const int cnt = min(128, end - chunk);
#pragma unroll
    for (int p = 0; p < 2; ++p) {
      const int h = w + p * 4;
      const float sd = sdl[h], m = mh[h], rd = rdh[h];
      for (int i = lane; i < cnt; i += 64) {
        float e = s1s[(size_t)cols[chunk + i] * 8 + h] + sd;
        e = (e > 0.f) ? e : 0.2f * e;
        alph[i][h] = expf(e - m) * rd;
      }
    }
    __syncthreads();
    if (t < 192) {
      for (int i = 0; i < cnt; ++i) {
        int src = cols[chunk + i];
        uint2 v = *(const uint2*)(xb + (size_t)src * kH + c0);
        float f0 = blo(v.x), f1 = bhi(v.x), f2 = blo(v.y), f3 = bhi(v.y);
#pragma unroll
        for (int h = 0; h < 8; ++h) {
          float a = alph[i][h];
          acc[h][0] = fmaf(a, f0, acc[h][0]);
          acc[h][1] = fmaf(a, f1, acc[h][1]);
          acc[h][2] = fmaf(a, f2, acc[h][2]);
          acc[h][3] = fmaf(a, f3, acc[h][3]);
        }
      }
    }
    __syncthreads();
  }
  if (t < 192) {
#pragma unroll
    for (int h = 0; h < 8; ++h) {
      uint2 o;
      o.x = pk2(acc[h][0], acc[h][1]);
      o.y = pk2(acc[h][2], acc[h][3]);
      *(uint2*)(y + ((size_t)n * 8 + h) * kH + c0) = o;
    }
  }
}

// ---------------- GAT layer-2 segment softmax + aggregation ----------------
__global__ __launch_bounds__(256) void gat_agg_kernel(
    const int* __restrict__ rowptr, const int* __restrict__ cols,
    const float* __restrict__ s_src, const float* __restrict__ s_dst,
    const __hip_bfloat16* __restrict__ h, const float* __restrict__ bias,
    float* __restrict__ out_f, int total) {
  const int pair = blockIdx.x * 4 + (threadIdx.x >> 6);
  if (pair >= total) return;
  const int lane = threadIdx.x & 63;
  const int n = pair;
  const int beg = rowptr[n], end = rowptr[n + 1];
  const float sdv = s_dst[pair];

  float m = -3.402823466e38f;
  for (int i = beg + lane; i < end; i += 64) {
    float e = s_src[cols[i]] + sdv;
    e = (e > 0.f) ? e : 0.2f * e;
    m = fmaxf(m, e);
  }
#pragma unroll
  for (int o = 32; o; o >>= 1) m = fmaxf(m, __shfl_xor(m, o));

  float dsum = 0.f;
  for (int i = beg + lane; i < end; i += 64) {
    float e = s_src[cols[i]] + sdv;
    e = (e > 0.f) ? e : 0.2f * e;
    dsum += expf(e - m);
  }
#pragma unroll
  for (int o = 32; o; o >>= 1) dsum += __shfl_xor(dsum, o);
  const float rdsum = 1.f / (dsum + 1e-16f);

  float a[12];
#pragma unroll
  for (int q = 0; q < 12; ++q) a[q] = 0.f;
  const size_t hoff = (size_t)lane * 4;
  for (int i = beg; i < end; ++i) {
    int src = cols[i];
    float e = s_src[src] + sdv;
    e = (e > 0.f) ? e : 0.2f * e;
    float wgt = expf(e - m) * rdsum;
    const __hip_bfloat16* hp = h + (size_t)src * kH + hoff;
#pragma unroll
    for (int j = 0; j < 3; ++j) {
      uint2 v = *(const uint2*)(hp + j * 256);
      a[j * 4 + 0] = fmaf(wgt, blo(v.x), a[j * 4 + 0]);
      a[j * 4 + 1] = fmaf(wgt, bhi(v.x), a[j * 4 + 1]);
      a[j * 4 + 2] = fmaf(wgt, blo(v.y), a[j * 4 + 2]);
      a[j * 4 + 3] = fmaf(wgt, bhi(v.y), a[j * 4 + 3]);
    }
  }
  const size_t ob = (size_t)n * kH + hoff;
#pragma unroll
  for (int j = 0; j < 3; ++j) {
#pragma unroll
    for (int q = 0; q < 4; ++q)
      out_f[ob + j * 256 + q] = a[j * 4 + q] + bias[hoff + j * 256 + q];
  }
}

// ---------------- MLP head ----------------
__global__ void cat_kernel(const float* __restrict__ xf, const float* __restrict__ text_emb,
                           const float* __restrict__ img_emb, const int* __restrict__ user_idx,
                           const int* __restrict__ business_idx, __hip_bfloat16* __restrict__ cat) {
  int b = blockIdx.x;
  int u = user_idx[b], z = business_idx[b];
  __hip_bfloat16* crow = cat + (size_t)b * 4 * kH;
  for (int c = threadIdx.x; c < kH; c += blockDim.x) {
    crow[c] = __float2bfloat16(xf[(size_t)u * kH + c]);
    crow[kH + c] = __float2bfloat16(xf[(size_t)z * kH + c]);
    crow[2 * kH + c] = __float2bfloat16(text_emb[(size_t)b * kH + c]);
    crow[3 * kH + c] = __float2bfloat16(img_emb[(size_t)b * kH + c]);
  }
}

}  // namespace

extern "C" void kernel_launch(void* const* d_in, const int* in_sizes, int n_in,
                              void* d_out, int out_size, void* d_ws, size_t ws_size,
                              hipStream_t stream) {
  const float* text_cls = (const float*)d_in[0];
  const float* img_cls = (const float*)d_in[1];
  const float* biz_feats = (const float*)d_in[2];
  const float* W_text = (const float*)d_in[3];
  const float* b_text = (const float*)d_in[4];
  const float* W_img = (const float*)d_in[5];
  const float* b_img = (const float*)d_in[6];
  const float* W_bf = (const float*)d_in[7];
  const float* b_bf = (const float*)d_in[8];
  const float* user_table = (const float*)d_in[9];
  const float* biz_table = (const float*)d_in[10];
  const float* W1 = (const float*)d_in[11];
  const float* att_src1 = (const float*)d_in[12];
  const float* att_dst1 = (const float*)d_in[13];
  const float* b1 = (const float*)d_in[14];
  const float* W2 = (const float*)d_in[15];
  const float* att_src2 = (const float*)d_in[16];
  const float* att_dst2 = (const float*)d_in[17];
  const float* b2 = (const float*)d_in[18];
  const float* Wf1 = (const float*)d_in[19];
  const float* bf1 = (const float*)d_in[20];
  const float* Wf2 = (const float*)d_in[21];
  const float* bf2 = (const float*)d_in[22];
  const float* Wf3 = (const float*)d_in[23];
  const float* bf3 = (const float*)d_in[24];
  const int* user_idx = (const int*)d_in[25];
  const int* business_idx = (const int*)d_in[26];
  const int* edge_index = (const int*)d_in[27];
  float* out = (float*)d_out;
  (void)in_sizes; (void)n_in; (void)out_size; (void)ws_size;

  char* base = (char*)d_ws;
  size_t off = 0;
  auto alloc = [&](size_t bytes) -> void* {
    void* p = base + off;
    off = (off + bytes + 255) & ~(size_t)255;
    return p;
  };
  __hip_bfloat16* xb = (__hip_bfloat16*)alloc((size_t)kNN * kH * 2);
  __hip_bfloat16* text_bf = (__hip_bfloat16*)alloc((size_t)kB * kH * 2);
  __hip_bfloat16* imgm_bf = (__hip_bfloat16*)alloc((size_t)kB * kH * 2);
  float* text_emb = (float*)alloc((size_t)kB * kH * 4);
  float* img_emb = (float*)alloc((size_t)kB * kH * 4);
  __hip_bfloat16* Wtt = (__hip_bfloat16*)alloc((size_t)kH * kH * 2);
  __hip_bfloat16* Wit = (__hip_bfloat16*)alloc((size_t)kH * kH * 2);
  __hip_bfloat16* W1t = (__hip_bfloat16*)alloc((size_t)kHeads * kH * kH * 2);
  __hip_bfloat16* W2t = (__hip_bfloat16*)alloc((size_t)kH * kHeads * kH * 2);
  __hip_bfloat16* Wf1t = (__hip_bfloat16*)alloc((size_t)2 * kH * 4 * kH * 2);
  __hip_bfloat16* Wf2t = (__hip_bfloat16*)alloc((size_t)kH * 2 * kH * 2);
  float* wa = (float*)alloc((size_t)2 * kHeads * kH * 4);
  // y region (37.75MB): agg1x->gemm_head; reused as kpin bf16 partials (S=8,
  // exact fit) and later Wf1/Wf2 f32 partials.
  __hip_bfloat16* y = (__hip_bfloat16*)alloc((size_t)kNN * kHeads * kH * 2);
  // ext region: xf/catb/m1 (live only after kpin partials consumed)
  char* ext = (char*)alloc(9437184 + 6291456 + 3145728);
  __hip_bfloat16* part = (__hip_bfloat16*)y;
  float* xf = (float*)ext;
  __hip_bfloat16* catb = (__hip_bfloat16*)(ext + 9437184);
  __hip_bfloat16* m1 = (__hip_bfloat16*)(ext + 9437184 + 6291456);
  __hip_bfloat16* x2 = (__hip_bfloat16*)alloc((size_t)kNN * kHeads * kH * 2);
  __hip_bfloat16* h2 = (__hip_bfloat16*)alloc((size_t)kNN * kH * 2);
  float* s1s = (float*)alloc((size_t)kNN * kHeads * 4);  // contiguous with s1d
  float* s1d = (float*)alloc((size_t)kNN * kHeads * 4);
  float* s2s = (float*)alloc((size_t)kNN * 4);
  float* s2d = (float*)alloc((size_t)kNN * 4);
  int* rowptr = (int*)alloc((size_t)(kNN + 1) * 4);
  int* cursor = (int*)alloc((size_t)kNN * 4);
  int* cols = (int*)alloc((size_t)kET * 4);
  (void)s1d;

  // mega1: weight transposes + input prep + wa1 + init(xb, s1s/s1d) + CSR scan
  TJobs tj;
  tj.in[0] = W_text; tj.out[0] = Wtt;  tj.K[0] = kH;          tj.N[0] = kH;
  tj.in[1] = W_img;  tj.out[1] = Wit;  tj.K[1] = kH;          tj.N[1] = kH;
  tj.in[2] = W1;     tj.out[2] = W1t;  tj.K[2] = kH;          tj.N[2] = kHeads * kH;
  tj.in[3] = W2;     tj.out[3] = W2t;  tj.K[3] = kHeads * kH; tj.N[3] = kH;
  tj.in[4] = Wf1;    tj.out[4] = Wf1t; tj.K[4] = 4 * kH;      tj.N[4] = 2 * kH;
  tj.in[5] = Wf2;    tj.out[5] = Wf2t; tj.K[5] = 2 * kH;      tj.N[5] = kH;
  tj.start[0] = 0;
  for (int q = 0; q < 6; ++q)
    tj.start[q + 1] = tj.start[q] + (tj.K[q] / 32) * (tj.N[q] / 32);
  const int prep_blocks = (kB * kH + 255) / 256;
  const int wa_blocks = (kHeads * kH) / 4;
  const int init_blocks = (kNN * kH * 2 / 16 + 255) / 256;
  mega1_kernel<<<1 + tj.start[6] + prep_blocks + wa_blocks + init_blocks, 256, 0, stream>>>(
      tj, text_cls, img_cls, text_bf, imgm_bf, prep_blocks, W1, att_src1, att_dst1, wa,
      wa_blocks, (uint4*)xb, (uint4*)s1s, edge_index, rowptr, cursor);

  // mega2: encoder GEMMs + CSR fill + build_user(+scores)
  mega2_kernel<<<2 * kEncBlocks + kFillBlocks + kNU, 256, 0, stream>>>(
      text_bf, Wtt, b_text, text_emb, imgm_bf, Wit, b_img, img_emb,
      edge_index, cursor, cols, user_idx, user_table, wa, xb, s1s, s1d);

  // mega3: build_biz(+winner, +scores)
  mega3_kernel<<<kNB, 256, 0, stream>>>(business_idx, text_emb, img_emb, biz_feats,
                                        W_bf, b_bf, biz_table, wa, xb, s1s, s1d);

  // GAT layer 1, x-space: alpha-aggregate (768-dim) -> head-pinned GEMM
  agg1x_kernel<<<kNN, 256, 0, stream>>>(rowptr, cols, s1s, s1d, xb, y);
  gemm_head<128, 128, 4, 4><<<dim3(kHeads, (kNN / 128) * (kH / 128)), 256, 0, stream>>>(
      y, W1t, b1, x2);

  // GAT layer 2: K-chunk->XCD-pinned split-K (S=8, 128^2, bf16 partials),
  // fused reduce+scores2, aggregate
  mfma_gemm_kpin<128, 128, 4, 4, kS2>
      <<<dim3(kS2, (kNN / 128) * (kH / 128)), 256, 0, stream>>>(
          x2, W2t, part, kNN, kH, kHeads * kH);
  reduce_scores2_kernel<<<kNN, 192, 0, stream>>>(part, att_src2, att_dst2, h2, s2s, s2d);
  gat_agg_kernel<<<kNN / 4, 256, 0, stream>>>(rowptr, cols, s2s, s2d, h2, b2, xf, kNN);

  // MLP head: cat -> Wf1 (split-K S=2, f32 partials in y) -> Wf2 -> fused final
  cat_kernel<<<kB, 256, 0, stream>>>(xf, text_emb, img_emb, user_idx, business_idx, catb);
  mfma_gemm_splitk<64, 128, 2, 4><<<dim3(2 * kH / 128, kB / 64, 2), 256, 0, stream>>>(
      catb, Wf1t, (float*)y, kB, 2 * kH, 4 * kH, 2 * kH);
  reduce_relu_kernel<<<(kB * 2 * kH / 4 + 255) / 256, 256, 0, stream>>>(
      (float*)y, bf1, m1, kB * 2 * kH / 4, 2 * kH);
  mfma_gemm_splitk<64, 128, 2, 4><<<dim3(kH / 128, kB / 64, 2), 256, 0, stream>>>(
      m1, Wf2t, (float*)y, kB, kH, 2 * kH, kH);
  reduce_final_kernel<<<kB, 192, 0, stream>>>((float*)y, bf2, Wf3, bf3, out);
}